// Round 1
// baseline (665.807 us; speedup 1.0000x reference)
//
#include <hip/hip_runtime.h>
#include <math.h>

#define N_NODES 50000
#define E_EDGES 1600000
#define G_GRAPHS 512
#define IN_DIM 64
#define EMBED 128
#define HD 128
#define NHEAD 4
#define D1 128
#define D2 64
#define D3 16
#define NEG_SLOPE 0.2f

static __device__ __forceinline__ float leaky(float x) { return x > 0.f ? x : NEG_SLOPE * x; }
static __device__ __forceinline__ float elu(float x) { return x > 0.f ? x : expm1f(x); }
static __device__ __forceinline__ float compf(float4 v, int i) {
    return i == 0 ? v.x : (i == 1 ? v.y : (i == 2 ? v.z : v.w));
}

// K0: Wcomb = W0 @ Wfc (64x128), bcomb = b0 @ Wfc (128)
__global__ void k0_compose(const float* __restrict__ W0, const float* __restrict__ b0,
                           const float* __restrict__ Wfc, float* __restrict__ Wc,
                           float* __restrict__ bc) {
    int tid = blockIdx.x * blockDim.x + threadIdx.x;
    if (tid < IN_DIM * HD) {
        int i = tid >> 7, j = tid & 127;
        float acc = 0.f;
        for (int k = 0; k < EMBED; ++k) acc += W0[i * EMBED + k] * Wfc[k * HD + j];
        Wc[tid] = acc;
    } else if (tid < IN_DIM * HD + HD) {
        int j = tid - IN_DIM * HD;
        float acc = 0.f;
        for (int k = 0; k < EMBED; ++k) acc += b0[k] * Wfc[k * HD + j];
        bc[j] = acc;
    }
}

// K1: feat = feature @ Wc + bc   (N x 64) @ (64 x 128)
// block = 256 threads, 32 rows per block; thread: col c = t&127, row-half rr = t>>7
__global__ void __launch_bounds__(256) k1_gemm(const float* __restrict__ A,
                                               const float* __restrict__ W,
                                               const float* __restrict__ b,
                                               float* __restrict__ out) {
    __shared__ float Ws[IN_DIM * HD];     // 32 KB
    __shared__ float As[32][65];          // padded: bank-conflict-free
    const int t = threadIdx.x;
    const int c = t & 127, rr = t >> 7;
    const int row0 = blockIdx.x * 32;
    for (int i = t; i < IN_DIM * HD; i += 256) Ws[i] = W[i];
    for (int i = t; i < 32 * IN_DIM; i += 256) {
        int r = i >> 6, k = i & 63;
        int gr = row0 + r;
        As[r][k] = (gr < N_NODES) ? A[(size_t)gr * IN_DIM + k] : 0.f;
    }
    __syncthreads();
    float acc[16];
#pragma unroll
    for (int i = 0; i < 16; ++i) acc[i] = 0.f;
    for (int k = 0; k < IN_DIM; ++k) {
        float w = Ws[k * HD + c];
#pragma unroll
        for (int i = 0; i < 16; ++i) acc[i] += As[rr * 16 + i][k] * w;
    }
    const float bb = b[c];
#pragma unroll
    for (int i = 0; i < 16; ++i) {
        int gr = row0 + rr * 16 + i;
        if (gr < N_NODES) out[(size_t)gr * HD + c] = acc[i] + bb;
    }
}

// K2: el[n][h] = dot(feat[n,h*32:+32], attn_l[h]); er likewise. One wave per node.
__global__ void __launch_bounds__(256) k2_elr(const float* __restrict__ feat,
                                              const float* __restrict__ attn_l,
                                              const float* __restrict__ attn_r,
                                              float* __restrict__ el, float* __restrict__ er) {
    const int wid = threadIdx.x >> 6, lane = threadIdx.x & 63;
    const int n = blockIdx.x * 4 + wid;
    if (n >= N_NODES) return;
    const float2 f = *(const float2*)(feat + (size_t)n * HD + lane * 2);
    const float2 al = *(const float2*)(attn_l + lane * 2);
    const float2 ar = *(const float2*)(attn_r + lane * 2);
    float pl = f.x * al.x + f.y * al.y;
    float pr = f.x * ar.x + f.y * ar.y;
#pragma unroll
    for (int off = 8; off; off >>= 1) {
        pl += __shfl_xor(pl, off);
        pr += __shfl_xor(pr, off);
    }
    if ((lane & 15) == 0) {
        el[n * 4 + (lane >> 4)] = pl;
        er[n * 4 + (lane >> 4)] = pr;
    }
}

// K3: in-degree count
__global__ void k3_deg(const int* __restrict__ dst, int* __restrict__ deg) {
    int e = blockIdx.x * 256 + threadIdx.x;
    if (e < E_EDGES) atomicAdd(deg + dst[e], 1);
}

// K4: exclusive scan of deg -> rowstart (single block, 1024 threads, sequential chunks)
__global__ void __launch_bounds__(1024) k4_scan(const int* __restrict__ deg,
                                                int* __restrict__ rowstart) {
    const int PER = (N_NODES + 1023) / 1024;  // 49
    const int t = threadIdx.x, lane = t & 63, wid = t >> 6;
    const int base = t * PER;
    int s = 0;
    for (int i = 0; i < PER; ++i) {
        int idx = base + i;
        if (idx < N_NODES) s += deg[idx];
    }
    int incl = s;
#pragma unroll
    for (int off = 1; off < 64; off <<= 1) {
        int o = __shfl_up(incl, off, 64);
        if (lane >= off) incl += o;
    }
    __shared__ int wsum[16], woff[16];
    if (lane == 63) wsum[wid] = incl;
    __syncthreads();
    if (t < 16) {
        int v = wsum[t];
        int iv = v;
#pragma unroll
        for (int off = 1; off < 16; off <<= 1) {
            int o = __shfl_up(iv, off, 64);
            if (t >= off) iv += o;
        }
        woff[t] = iv - v;
    }
    __syncthreads();
    int run = woff[wid] + incl - s;
    for (int i = 0; i < PER; ++i) {
        int idx = base + i;
        if (idx < N_NODES) {
            rowstart[idx] = run;
            run += deg[idx];
        }
    }
    if (t == 0) rowstart[N_NODES] = E_EDGES;
}

// K5: fill CSR buckets with (edge_id, src)
__global__ void k5_fill(const int* __restrict__ src, const int* __restrict__ dst,
                        const int* __restrict__ rowstart, int* __restrict__ cursor,
                        int2* __restrict__ csr) {
    int e = blockIdx.x * 256 + threadIdx.x;
    if (e < E_EDGES) {
        int d = dst[e];
        int pos = atomicAdd(cursor + d, 1);
        csr[rowstart[d] + pos] = make_int2(e, src[e]);
    }
}

// K6: per-dst softmax + message aggregation + graph pooling. One wave per dst node.
__global__ void __launch_bounds__(256) k6_aggregate(
    const int2* __restrict__ csr, const int* __restrict__ rowstart,
    const float* __restrict__ el, const float* __restrict__ er,
    const float* __restrict__ feat, const float* __restrict__ gat_bias,
    const int* __restrict__ graph_ids, float* __restrict__ a_out,
    float* __restrict__ gsums, int* __restrict__ gcnt) {
    const int wid = threadIdx.x >> 6;
    const int lane = threadIdx.x & 63;
    const int n = blockIdx.x * 4 + wid;
    if (n >= N_NODES) return;
    const int start = rowstart[n];
    const int end = rowstart[n + 1];
    const float4 er4 = *(const float4*)(er + n * 4);

    // ---- pass 1a: per-head max (lane-strided over edges) ----
    float4 eh0 = make_float4(0.f, 0.f, 0.f, 0.f);
    const bool valid = (start + lane) < end;
    float4 mx = make_float4(-INFINITY, -INFINITY, -INFINITY, -INFINITY);
    if (valid) {
        int2 es = csr[start + lane];
        const float4 elv = *(const float4*)(el + es.y * 4);
        eh0.x = leaky(elv.x + er4.x);
        eh0.y = leaky(elv.y + er4.y);
        eh0.z = leaky(elv.z + er4.z);
        eh0.w = leaky(elv.w + er4.w);
        mx = eh0;
    }
    for (int e = start + lane + 64; e < end; e += 64) {  // rare (deg > 64)
        int2 es = csr[e];
        const float4 elv = *(const float4*)(el + es.y * 4);
        mx.x = fmaxf(mx.x, leaky(elv.x + er4.x));
        mx.y = fmaxf(mx.y, leaky(elv.y + er4.y));
        mx.z = fmaxf(mx.z, leaky(elv.z + er4.z));
        mx.w = fmaxf(mx.w, leaky(elv.w + er4.w));
    }
#pragma unroll
    for (int off = 32; off; off >>= 1) {
        mx.x = fmaxf(mx.x, __shfl_xor(mx.x, off));
        mx.y = fmaxf(mx.y, __shfl_xor(mx.y, off));
        mx.z = fmaxf(mx.z, __shfl_xor(mx.z, off));
        mx.w = fmaxf(mx.w, __shfl_xor(mx.w, off));
    }
    // ---- pass 1b: sum of exp ----
    float4 sm = make_float4(0.f, 0.f, 0.f, 0.f);
    if (valid) {
        sm.x = __expf(eh0.x - mx.x);
        sm.y = __expf(eh0.y - mx.y);
        sm.z = __expf(eh0.z - mx.z);
        sm.w = __expf(eh0.w - mx.w);
    }
    for (int e = start + lane + 64; e < end; e += 64) {  // rare
        int2 es = csr[e];
        const float4 elv = *(const float4*)(el + es.y * 4);
        sm.x += __expf(leaky(elv.x + er4.x) - mx.x);
        sm.y += __expf(leaky(elv.y + er4.y) - mx.y);
        sm.z += __expf(leaky(elv.z + er4.z) - mx.z);
        sm.w += __expf(leaky(elv.w + er4.w) - mx.w);
    }
#pragma unroll
    for (int off = 32; off; off >>= 1) {
        sm.x += __shfl_xor(sm.x, off);
        sm.y += __shfl_xor(sm.y, off);
        sm.z += __shfl_xor(sm.z, off);
        sm.w += __shfl_xor(sm.w, off);
    }
    float4 rd;
    rd.x = sm.x > 0.f ? 1.f / sm.x : 0.f;
    rd.y = sm.y > 0.f ? 1.f / sm.y : 0.f;
    rd.z = sm.z > 0.f ? 1.f / sm.z : 0.f;
    rd.w = sm.w > 0.f ? 1.f / sm.w : 0.f;

    // ---- pass 2: attention write + message accumulation ----
    // half-wave per edge: sub = which edge of the pair, j covers floats j*4..j*4+3
    const int sub = lane >> 5;
    const int j = lane & 31;
    const int h = j >> 3;
    const float erh = compf(er4, h);
    const float mxh = compf(mx, h);
    const float rdh = compf(rd, h);
    float4 acc = make_float4(0.f, 0.f, 0.f, 0.f);
    for (int e = start + sub; e < end; e += 2) {
        const int2 es = csr[e];
        const float elh = el[es.y * 4 + h];
        const float av = __expf(leaky(elh + erh) - mxh) * rdh;
        if ((j & 7) == 0) a_out[(size_t)es.x * 4 + h] = av;
        const float4 f = *(const float4*)(feat + (size_t)es.y * HD + j * 4);
        acc.x += av * f.x;
        acc.y += av * f.y;
        acc.z += av * f.z;
        acc.w += av * f.w;
    }
    acc.x += __shfl_xor(acc.x, 32);
    acc.y += __shfl_xor(acc.y, 32);
    acc.z += __shfl_xor(acc.z, 32);
    acc.w += __shfl_xor(acc.w, 32);
    if (lane < 32) {
        const float4 bb = *(const float4*)(gat_bias + lane * 4);
        const int g = graph_ids[n];
        float* gs = gsums + g * HD + lane * 4;
        atomicAdd(gs + 0, acc.x + bb.x);
        atomicAdd(gs + 1, acc.y + bb.y);
        atomicAdd(gs + 2, acc.z + bb.z);
        atomicAdd(gs + 3, acc.w + bb.w);
        if (lane == 0) atomicAdd(gcnt + g, 1);
    }
}

// K7: mean-pool finish + ELU MLP. One block (128 threads) per graph.
__global__ void __launch_bounds__(128) k7_mlp(
    const float* __restrict__ gsums, const int* __restrict__ gcnt,
    const float* __restrict__ W1, const float* __restrict__ b1,
    const float* __restrict__ W2, const float* __restrict__ b2,
    const float* __restrict__ W3, const float* __restrict__ b3,
    float* __restrict__ out) {
    __shared__ float x[HD], y[D1];
    const int g = blockIdx.x, t = threadIdx.x;
    const float cnt = fmaxf((float)gcnt[g], 1.f);
    x[t] = elu(gsums[g * HD + t] / cnt);
    __syncthreads();
    float acc = b1[t];
    for (int k = 0; k < HD; ++k) acc += x[k] * W1[k * D1 + t];
    y[t] = elu(acc);
    __syncthreads();
    if (t < D2) {
        float a2 = b2[t];
        for (int k = 0; k < D1; ++k) a2 += y[k] * W2[k * D2 + t];
        x[t] = elu(a2);
    }
    __syncthreads();
    if (t < D3) {
        float a3 = b3[t];
        for (int k = 0; k < D2; ++k) a3 += x[k] * W3[k * D3 + t];
        out[g * D3 + t] = a3;
    }
}

extern "C" void kernel_launch(void* const* d_in, const int* in_sizes, int n_in,
                              void* d_out, int out_size, void* d_ws, size_t ws_size,
                              hipStream_t stream) {
    const float* feature = (const float*)d_in[0];
    const int* src = (const int*)d_in[1];
    const int* dst = (const int*)d_in[2];
    const int* graph_ids = (const int*)d_in[3];
    const float* W0 = (const float*)d_in[4];
    const float* b0 = (const float*)d_in[5];
    const float* Wfc = (const float*)d_in[6];
    const float* attn_l = (const float*)d_in[7];
    const float* attn_r = (const float*)d_in[8];
    const float* gat_bias = (const float*)d_in[9];
    const float* W1 = (const float*)d_in[10];
    const float* b1 = (const float*)d_in[11];
    const float* W2 = (const float*)d_in[12];
    const float* b2 = (const float*)d_in[13];
    const float* W3 = (const float*)d_in[14];
    const float* b3 = (const float*)d_in[15];

    char* ws = (char*)d_ws;
    size_t off = 0;
    auto carve = [&](size_t bytes) -> void* {
        void* p = ws + off;
        off += (bytes + 255) & ~(size_t)255;
        return p;
    };
    // zero-initialized region first (single memset)
    int* deg = (int*)carve((size_t)N_NODES * 4);
    int* cursor = (int*)carve((size_t)N_NODES * 4);
    float* gsums = (float*)carve((size_t)G_GRAPHS * HD * 4);
    int* gcnt = (int*)carve((size_t)G_GRAPHS * 4);
    const size_t zero_span = off;
    float* Wc = (float*)carve((size_t)IN_DIM * HD * 4);
    float* bc = (float*)carve((size_t)HD * 4);
    float* feat = (float*)carve((size_t)N_NODES * HD * 4);
    float* el = (float*)carve((size_t)N_NODES * 4 * 4);
    float* er = (float*)carve((size_t)N_NODES * 4 * 4);
    int* rowstart = (int*)carve((size_t)(N_NODES + 1) * 4);
    int2* csr = (int2*)carve((size_t)E_EDGES * 8);

    float* out = (float*)d_out;
    float* a_out = out + G_GRAPHS * D3;  // atten follows out in the flat output

    hipMemsetAsync(d_ws, 0, zero_span, stream);
    k0_compose<<<(IN_DIM * HD + HD + 255) / 256, 256, 0, stream>>>(W0, b0, Wfc, Wc, bc);
    k1_gemm<<<(N_NODES + 31) / 32, 256, 0, stream>>>(feature, Wc, bc, feat);
    k2_elr<<<(N_NODES + 3) / 4, 256, 0, stream>>>(feat, attn_l, attn_r, el, er);
    k3_deg<<<(E_EDGES + 255) / 256, 256, 0, stream>>>(dst, deg);
    k4_scan<<<1, 1024, 0, stream>>>(deg, rowstart);
    k5_fill<<<(E_EDGES + 255) / 256, 256, 0, stream>>>(src, dst, rowstart, cursor, csr);
    k6_aggregate<<<(N_NODES + 3) / 4, 256, 0, stream>>>(csr, rowstart, el, er, feat,
                                                        gat_bias, graph_ids, a_out, gsums, gcnt);
    k7_mlp<<<G_GRAPHS, 128, 0, stream>>>(gsums, gcnt, W1, b1, W2, b2, W3, b3, out);
}

// Round 3
// 466.569 us; speedup vs baseline: 1.4270x; 1.4270x over previous
//
#include <hip/hip_runtime.h>
#include <math.h>

#define N_NODES 50000
#define E_EDGES 1600000
#define G_GRAPHS 512
#define IN_DIM 64
#define EMBED 128
#define HD 128
#define NHEAD 4
#define D1 128
#define D2 64
#define D3 16
#define NEG_SLOPE 0.2f
#define SCAN_BLOCKS ((N_NODES + 255) / 256)   // 196

static __device__ __forceinline__ float leaky(float x) { return x > 0.f ? x : NEG_SLOPE * x; }
static __device__ __forceinline__ float compf(float4 v, int i) {
    return i == 0 ? v.x : (i == 1 ? v.y : (i == 2 ? v.z : v.w));
}

// K0: Wcomb = W0 @ Wfc (64x128), bcomb = b0 @ Wfc (128)
__global__ void k0_compose(const float* __restrict__ W0, const float* __restrict__ b0,
                           const float* __restrict__ Wfc, float* __restrict__ Wc,
                           float* __restrict__ bc) {
    int tid = blockIdx.x * blockDim.x + threadIdx.x;
    if (tid < IN_DIM * HD) {
        int i = tid >> 7, j = tid & 127;
        float acc = 0.f;
        for (int k = 0; k < EMBED; ++k) acc += W0[i * EMBED + k] * Wfc[k * HD + j];
        Wc[tid] = acc;
    } else if (tid < IN_DIM * HD + HD) {
        int j = tid - IN_DIM * HD;
        float acc = 0.f;
        for (int k = 0; k < EMBED; ++k) acc += b0[k] * Wfc[k * HD + j];
        bc[j] = acc;
    }
}

// K1: feat = feature @ Wc + bc   (N x 64) @ (64 x 128)
__global__ void __launch_bounds__(256) k1_gemm(const float* __restrict__ A,
                                               const float* __restrict__ W,
                                               const float* __restrict__ b,
                                               float* __restrict__ out) {
    __shared__ float Ws[IN_DIM * HD];
    __shared__ float As[32][65];
    const int t = threadIdx.x;
    const int c = t & 127, rr = t >> 7;
    const int row0 = blockIdx.x * 32;
    for (int i = t; i < IN_DIM * HD; i += 256) Ws[i] = W[i];
    for (int i = t; i < 32 * IN_DIM; i += 256) {
        int r = i >> 6, k = i & 63;
        int gr = row0 + r;
        As[r][k] = (gr < N_NODES) ? A[(size_t)gr * IN_DIM + k] : 0.f;
    }
    __syncthreads();
    float acc[16];
#pragma unroll
    for (int i = 0; i < 16; ++i) acc[i] = 0.f;
    for (int k = 0; k < IN_DIM; ++k) {
        float w = Ws[k * HD + c];
#pragma unroll
        for (int i = 0; i < 16; ++i) acc[i] += As[rr * 16 + i][k] * w;
    }
    const float bb = b[c];
#pragma unroll
    for (int i = 0; i < 16; ++i) {
        int gr = row0 + rr * 16 + i;
        if (gr < N_NODES) out[(size_t)gr * HD + c] = acc[i] + bb;
    }
}

// K2: el/er per node. One wave per node.
__global__ void __launch_bounds__(256) k2_elr(const float* __restrict__ feat,
                                              const float* __restrict__ attn_l,
                                              const float* __restrict__ attn_r,
                                              float* __restrict__ el, float* __restrict__ er) {
    const int wid = threadIdx.x >> 6, lane = threadIdx.x & 63;
    const int n = blockIdx.x * 4 + wid;
    if (n >= N_NODES) return;
    const float2 f = *(const float2*)(feat + (size_t)n * HD + lane * 2);
    const float2 al = *(const float2*)(attn_l + lane * 2);
    const float2 ar = *(const float2*)(attn_r + lane * 2);
    float pl = f.x * al.x + f.y * al.y;
    float pr = f.x * ar.x + f.y * ar.y;
#pragma unroll
    for (int off = 8; off; off >>= 1) {
        pl += __shfl_xor(pl, off);
        pr += __shfl_xor(pr, off);
    }
    if ((lane & 15) == 0) {
        el[n * 4 + (lane >> 4)] = pl;
        er[n * 4 + (lane >> 4)] = pr;
    }
}

// K3: in-degree count
__global__ void k3_deg(const int* __restrict__ dst, int* __restrict__ deg) {
    int e = blockIdx.x * 256 + threadIdx.x;
    if (e < E_EDGES) atomicAdd(deg + dst[e], 1);
}

// K4a: per-block (256-elem chunk) sums of deg
__global__ void __launch_bounds__(256) k4a_partial(const int* __restrict__ deg,
                                                   int* __restrict__ partial) {
    const int t = threadIdx.x, i = blockIdx.x * 256 + t;
    const int lane = t & 63, wid = t >> 6;
    int v = (i < N_NODES) ? deg[i] : 0;
    int s = v;
#pragma unroll
    for (int off = 32; off; off >>= 1) s += __shfl_xor(s, off);
    __shared__ int ws[4];
    if (lane == 0) ws[wid] = s;
    __syncthreads();
    if (t == 0) partial[blockIdx.x] = ws[0] + ws[1] + ws[2] + ws[3];
}

// K4b: exclusive scan of the 196 partials (single block)
__global__ void __launch_bounds__(256) k4b_scanpart(int* __restrict__ partial) {
    const int t = threadIdx.x, lane = t & 63, wid = t >> 6;
    int v = (t < SCAN_BLOCKS) ? partial[t] : 0;
    int incl = v;
#pragma unroll
    for (int off = 1; off < 64; off <<= 1) {
        int o = __shfl_up(incl, off, 64);
        if (lane >= off) incl += o;
    }
    __shared__ int ws[4];
    if (lane == 63) ws[wid] = incl;
    __syncthreads();
    int base = 0;
    for (int i = 0; i < wid; ++i) base += ws[i];
    if (t < SCAN_BLOCKS) partial[t] = base + incl - v;
}

// K4c: per-block exclusive scan + block offset -> rowstart
__global__ void __launch_bounds__(256) k4c_scan(const int* __restrict__ deg,
                                                const int* __restrict__ partial,
                                                int* __restrict__ rowstart) {
    const int t = threadIdx.x, i = blockIdx.x * 256 + t;
    const int lane = t & 63, wid = t >> 6;
    int v = (i < N_NODES) ? deg[i] : 0;
    int incl = v;
#pragma unroll
    for (int off = 1; off < 64; off <<= 1) {
        int o = __shfl_up(incl, off, 64);
        if (lane >= off) incl += o;
    }
    __shared__ int ws[4];
    if (lane == 63) ws[wid] = incl;
    __syncthreads();
    int base = partial[blockIdx.x];
    for (int w = 0; w < wid; ++w) base += ws[w];
    if (i < N_NODES) rowstart[i] = base + incl - v;
    if (i == 0) rowstart[N_NODES] = E_EDGES;
}

// K5: fill CSR buckets with src
__global__ void k5_fill(const int* __restrict__ src, const int* __restrict__ dst,
                        const int* __restrict__ rowstart, int* __restrict__ cursor,
                        int* __restrict__ csr_src) {
    int e = blockIdx.x * 256 + threadIdx.x;
    if (e < E_EDGES) {
        int d = dst[e];
        int pos = atomicAdd(cursor + d, 1);
        csr_src[rowstart[d] + pos] = src[e];
    }
}

// K6: per-dst softmax stats + message aggregation. One wave per dst.
// Writes per-node (max, 1/denom) to mrd for K6b, and hn = rst + gat_bias.
__global__ void __launch_bounds__(256) k6_aggregate(
    const int* __restrict__ csr_src, const int* __restrict__ rowstart,
    const float* __restrict__ el, const float* __restrict__ er,
    const float* __restrict__ feat, const float* __restrict__ gat_bias,
    float* __restrict__ mrd, float* __restrict__ hn) {
    const int wid = threadIdx.x >> 6;
    const int lane = threadIdx.x & 63;
    const int n = blockIdx.x * 4 + wid;
    if (n >= N_NODES) return;
    const int start = rowstart[n];
    const int end = rowstart[n + 1];
    const int deg = end - start;
    const float4 er4 = *(const float4*)(er + n * 4);

    // ---- pass 1: per-head max + exp-sum; lane l owns edge start+l (deg<=64 case) ----
    int esrc = 0;
    float4 eh0 = make_float4(0.f, 0.f, 0.f, 0.f);
    const bool valid = lane < deg;
    float4 mx = make_float4(-INFINITY, -INFINITY, -INFINITY, -INFINITY);
    if (valid) {
        esrc = csr_src[start + lane];
        const float4 elv = *(const float4*)(el + esrc * 4);
        eh0.x = leaky(elv.x + er4.x);
        eh0.y = leaky(elv.y + er4.y);
        eh0.z = leaky(elv.z + er4.z);
        eh0.w = leaky(elv.w + er4.w);
        mx = eh0;
    }
    for (int e = start + lane + 64; e < end; e += 64) {  // deg>64: essentially never
        int s = csr_src[e];
        const float4 elv = *(const float4*)(el + s * 4);
        mx.x = fmaxf(mx.x, leaky(elv.x + er4.x));
        mx.y = fmaxf(mx.y, leaky(elv.y + er4.y));
        mx.z = fmaxf(mx.z, leaky(elv.z + er4.z));
        mx.w = fmaxf(mx.w, leaky(elv.w + er4.w));
    }
#pragma unroll
    for (int off = 32; off; off >>= 1) {
        mx.x = fmaxf(mx.x, __shfl_xor(mx.x, off));
        mx.y = fmaxf(mx.y, __shfl_xor(mx.y, off));
        mx.z = fmaxf(mx.z, __shfl_xor(mx.z, off));
        mx.w = fmaxf(mx.w, __shfl_xor(mx.w, off));
    }
    float4 sm = make_float4(0.f, 0.f, 0.f, 0.f);
    if (valid) {
        sm.x = __expf(eh0.x - mx.x);
        sm.y = __expf(eh0.y - mx.y);
        sm.z = __expf(eh0.z - mx.z);
        sm.w = __expf(eh0.w - mx.w);
    }
    for (int e = start + lane + 64; e < end; e += 64) {
        int s = csr_src[e];
        const float4 elv = *(const float4*)(el + s * 4);
        sm.x += __expf(leaky(elv.x + er4.x) - mx.x);
        sm.y += __expf(leaky(elv.y + er4.y) - mx.y);
        sm.z += __expf(leaky(elv.z + er4.z) - mx.z);
        sm.w += __expf(leaky(elv.w + er4.w) - mx.w);
    }
#pragma unroll
    for (int off = 32; off; off >>= 1) {
        sm.x += __shfl_xor(sm.x, off);
        sm.y += __shfl_xor(sm.y, off);
        sm.z += __shfl_xor(sm.z, off);
        sm.w += __shfl_xor(sm.w, off);
    }
    float4 rd;
    rd.x = sm.x > 0.f ? 1.f / sm.x : 0.f;
    rd.y = sm.y > 0.f ? 1.f / sm.y : 0.f;
    rd.z = sm.z > 0.f ? 1.f / sm.z : 0.f;
    rd.w = sm.w > 0.f ? 1.f / sm.w : 0.f;
    if (lane == 0) {
        ((float4*)mrd)[(size_t)n * 2] = mx;
        ((float4*)mrd)[(size_t)n * 2 + 1] = rd;
    }

    // ---- pass 2: 16 lanes per edge, 4 edges in flight per wave ----
    const int g4 = lane >> 4, gl = lane & 15;
    const int ha = gl >> 3;      // head for floats [gl*4, gl*4+3]
    const int hb = ha + 2;       // head for floats [64+gl*4, ...]
    const float mA = compf(mx, ha), rA = compf(rd, ha);
    const float mB = compf(mx, hb), rB = compf(rd, hb);
    float4 acc0 = make_float4(0.f, 0.f, 0.f, 0.f);
    float4 acc1 = make_float4(0.f, 0.f, 0.f, 0.f);

    if (deg <= 64) {
        // uniform trip count: ALL lanes iterate together -> shfl always well-defined
        const int iters = (deg + 3) >> 2;
        int idx = g4;
        for (int it = 0; it < iters; ++it, idx += 4) {
            const bool act = idx < deg;
            const int sidx = act ? idx : 0;
            const int cs = __shfl(esrc, sidx);
            const float eA0 = __shfl(eh0.x, sidx);
            const float eA1 = __shfl(eh0.y, sidx);
            const float eB0 = __shfl(eh0.z, sidx);
            const float eB1 = __shfl(eh0.w, sidx);
            const float4* fp = (const float4*)(feat + (size_t)cs * HD);
            const float4 f0 = fp[gl];
            const float4 f1 = fp[gl + 16];
            const float avA = act ? __expf((ha ? eA1 : eA0) - mA) * rA : 0.f;
            const float avB = act ? __expf((ha ? eB1 : eB0) - mB) * rB : 0.f;
            acc0.x += avA * f0.x; acc0.y += avA * f0.y;
            acc0.z += avA * f0.z; acc0.w += avA * f0.w;
            acc1.x += avB * f1.x; acc1.y += avB * f1.y;
            acc1.z += avB * f1.z; acc1.w += avB * f1.w;
        }
    } else {
        for (int e = start + g4; e < end; e += 4) {
            const int s = csr_src[e];
            const float4 elv = *(const float4*)(el + s * 4);
            const float ehA = leaky(compf(elv, ha) + compf(er4, ha));
            const float ehB = leaky(compf(elv, hb) + compf(er4, hb));
            const float avA = __expf(ehA - mA) * rA;
            const float avB = __expf(ehB - mB) * rB;
            const float4* fp = (const float4*)(feat + (size_t)s * HD);
            const float4 f0 = fp[gl], f1 = fp[gl + 16];
            acc0.x += avA * f0.x; acc0.y += avA * f0.y;
            acc0.z += avA * f0.z; acc0.w += avA * f0.w;
            acc1.x += avB * f1.x; acc1.y += avB * f1.y;
            acc1.z += avB * f1.z; acc1.w += avB * f1.w;
        }
    }
#pragma unroll
    for (int off = 16; off <= 32; off <<= 1) {
        acc0.x += __shfl_xor(acc0.x, off);
        acc0.y += __shfl_xor(acc0.y, off);
        acc0.z += __shfl_xor(acc0.z, off);
        acc0.w += __shfl_xor(acc0.w, off);
        acc1.x += __shfl_xor(acc1.x, off);
        acc1.y += __shfl_xor(acc1.y, off);
        acc1.z += __shfl_xor(acc1.z, off);
        acc1.w += __shfl_xor(acc1.w, off);
    }
    if (lane < 16) {
        const float4 b0 = ((const float4*)gat_bias)[gl];
        const float4 b1 = ((const float4*)gat_bias)[gl + 16];
        float4* hp = (float4*)(hn + (size_t)n * HD);
        hp[gl] = make_float4(acc0.x + b0.x, acc0.y + b0.y, acc0.z + b0.z, acc0.w + b0.w);
        hp[gl + 16] = make_float4(acc1.x + b1.x, acc1.y + b1.y, acc1.z + b1.z, acc1.w + b1.w);
    }
}

// K6b: attention coefficients in edge order (coalesced writes)
__global__ void __launch_bounds__(256) k6b_attn(
    const int* __restrict__ src, const int* __restrict__ dst,
    const float* __restrict__ el, const float* __restrict__ er,
    const float* __restrict__ mrd, float4* __restrict__ a_out) {
    int e = blockIdx.x * 256 + threadIdx.x;
    if (e >= E_EDGES) return;
    const int s = src[e], d = dst[e];
    const float4 el4 = *(const float4*)(el + s * 4);
    const float4 er4 = *(const float4*)(er + d * 4);
    const float4 m4 = ((const float4*)mrd)[(size_t)d * 2];
    const float4 r4 = ((const float4*)mrd)[(size_t)d * 2 + 1];
    float4 a;
    a.x = __expf(leaky(el4.x + er4.x) - m4.x) * r4.x;
    a.y = __expf(leaky(el4.y + er4.y) - m4.y) * r4.y;
    a.z = __expf(leaky(el4.z + er4.z) - m4.z) * r4.z;
    a.w = __expf(leaky(el4.w + er4.w) - m4.w) * r4.w;
    a_out[e] = a;
}

// K7: deterministic f64 mean-pool (graph_ids sorted -> contiguous ranges) + f64 MLP.
// 512 threads: 4-way node split per graph, combine in fixed order.
__global__ void __launch_bounds__(512) k7_pool_mlp(
    const float* __restrict__ hn, const int* __restrict__ graph_ids,
    const float* __restrict__ W1, const float* __restrict__ b1,
    const float* __restrict__ W2, const float* __restrict__ b2,
    const float* __restrict__ W3, const float* __restrict__ b3,
    float* __restrict__ out) {
    const int g = blockIdx.x, t = threadIdx.x;
    const int tt = t & 127, part = t >> 7;
    __shared__ int bounds[2];
    __shared__ double pool[4][128];
    __shared__ double x[128], y[128];
    if (t < 2) {
        const int target = g + t;
        int lo = 0, hi = N_NODES;
        while (lo < hi) {
            int mid = (lo + hi) >> 1;
            if (graph_ids[mid] < target) lo = mid + 1; else hi = mid;
        }
        bounds[t] = lo;
    }
    __syncthreads();
    const int lo = bounds[0], hi = bounds[1];
    double s = 0.0;
    for (int n = lo + part; n < hi; n += 4) s += (double)hn[(size_t)n * HD + tt];
    pool[part][tt] = s;
    __syncthreads();
    if (t < 128) {
        const double cnt = (double)(hi - lo);
        const double sum = pool[0][t] + pool[1][t] + pool[2][t] + pool[3][t];
        const double v = sum / fmax(cnt, 1.0);
        x[t] = v > 0.0 ? v : expm1(v);
    }
    __syncthreads();
    if (t < 128) {
        double acc = (double)b1[t];
        for (int k = 0; k < HD; ++k) acc += x[k] * (double)W1[k * D1 + t];
        y[t] = acc > 0.0 ? acc : expm1(acc);
    }
    __syncthreads();
    if (t < D2) {
        double a2 = (double)b2[t];
        for (int k = 0; k < D1; ++k) a2 += y[k] * (double)W2[k * D2 + t];
        x[t] = a2 > 0.0 ? a2 : expm1(a2);
    }
    __syncthreads();
    if (t < D3) {
        double a3 = (double)b3[t];
        for (int k = 0; k < D2; ++k) a3 += x[k] * (double)W3[k * D3 + t];
        out[g * D3 + t] = (float)a3;
    }
}

extern "C" void kernel_launch(void* const* d_in, const int* in_sizes, int n_in,
                              void* d_out, int out_size, void* d_ws, size_t ws_size,
                              hipStream_t stream) {
    const float* feature = (const float*)d_in[0];
    const int* src = (const int*)d_in[1];
    const int* dst = (const int*)d_in[2];
    const int* graph_ids = (const int*)d_in[3];
    const float* W0 = (const float*)d_in[4];
    const float* b0 = (const float*)d_in[5];
    const float* Wfc = (const float*)d_in[6];
    const float* attn_l = (const float*)d_in[7];
    const float* attn_r = (const float*)d_in[8];
    const float* gat_bias = (const float*)d_in[9];
    const float* W1 = (const float*)d_in[10];
    const float* b1 = (const float*)d_in[11];
    const float* W2 = (const float*)d_in[12];
    const float* b2 = (const float*)d_in[13];
    const float* W3 = (const float*)d_in[14];
    const float* b3 = (const float*)d_in[15];

    char* ws = (char*)d_ws;
    size_t off = 0;
    auto carve = [&](size_t bytes) -> void* {
        void* p = ws + off;
        off += (bytes + 255) & ~(size_t)255;
        return p;
    };
    // zero-initialized region first (single memset)
    int* deg = (int*)carve((size_t)N_NODES * 4);
    int* cursor = (int*)carve((size_t)N_NODES * 4);
    const size_t zero_span = off;
    float* Wc = (float*)carve((size_t)IN_DIM * HD * 4);
    float* bc = (float*)carve((size_t)HD * 4);
    float* feat = (float*)carve((size_t)N_NODES * HD * 4);
    float* el = (float*)carve((size_t)N_NODES * 4 * 4);
    float* er = (float*)carve((size_t)N_NODES * 4 * 4);
    int* rowstart = (int*)carve((size_t)(N_NODES + 1) * 4);
    int* partial = (int*)carve((size_t)SCAN_BLOCKS * 4);
    int* csr_src = (int*)carve((size_t)E_EDGES * 4);
    float* mrd = (float*)carve((size_t)N_NODES * 8 * 4);

    float* out = (float*)d_out;
    // atten region of d_out doubles as hn scratch: K6 writes hn, K7 reads it,
    // THEN K6b overwrites the region with the final attention output.
    // (N*HD == E*NHEAD == 6.4M floats exactly.)
    float* hn = out + G_GRAPHS * D3;
    float4* a_out = (float4*)hn;

    hipMemsetAsync(d_ws, 0, zero_span, stream);
    k0_compose<<<(IN_DIM * HD + HD + 255) / 256, 256, 0, stream>>>(W0, b0, Wfc, Wc, bc);
    k1_gemm<<<(N_NODES + 31) / 32, 256, 0, stream>>>(feature, Wc, bc, feat);
    k2_elr<<<(N_NODES + 3) / 4, 256, 0, stream>>>(feat, attn_l, attn_r, el, er);
    k3_deg<<<(E_EDGES + 255) / 256, 256, 0, stream>>>(dst, deg);
    k4a_partial<<<SCAN_BLOCKS, 256, 0, stream>>>(deg, partial);
    k4b_scanpart<<<1, 256, 0, stream>>>(partial);
    k4c_scan<<<SCAN_BLOCKS, 256, 0, stream>>>(deg, partial, rowstart);
    k5_fill<<<(E_EDGES + 255) / 256, 256, 0, stream>>>(src, dst, rowstart, cursor, csr_src);
    k6_aggregate<<<(N_NODES + 3) / 4, 256, 0, stream>>>(csr_src, rowstart, el, er, feat,
                                                        gat_bias, mrd, hn);
    k7_pool_mlp<<<G_GRAPHS, 512, 0, stream>>>(hn, graph_ids, W1, b1, W2, b2, W3, b3, out);
    k6b_attn<<<(E_EDGES + 255) / 256, 256, 0, stream>>>(src, dst, el, er, mrd, a_out);
}

// Round 5
// 416.633 us; speedup vs baseline: 1.5981x; 1.1199x over previous
//
#include <hip/hip_runtime.h>
#include <hip/hip_fp16.h>
#include <math.h>

#define N_NODES 50000
#define E_EDGES 1600000
#define G_GRAPHS 512
#define IN_DIM 64
#define EMBED 128
#define HD 128
#define NHEAD 4
#define D1 128
#define D2 64
#define D3 16
#define NEG_SLOPE 0.2f
#define SCAN_BLOCKS ((N_NODES + 255) / 256)   // 196

typedef float vfloat4 __attribute__((ext_vector_type(4)));

static __device__ __forceinline__ float leaky(float x) { return x > 0.f ? x : NEG_SLOPE * x; }
static __device__ __forceinline__ float compf(float4 v, int i) {
    return i == 0 ? v.x : (i == 1 ? v.y : (i == 2 ? v.z : v.w));
}

// K0: Wcomb = W0 @ Wfc (64x128), bcomb = b0 @ Wfc (128)
__global__ void k0_compose(const float* __restrict__ W0, const float* __restrict__ b0,
                           const float* __restrict__ Wfc, float* __restrict__ Wc,
                           float* __restrict__ bc) {
    int tid = blockIdx.x * blockDim.x + threadIdx.x;
    if (tid < IN_DIM * HD) {
        int i = tid >> 7, j = tid & 127;
        float acc = 0.f;
        for (int k = 0; k < EMBED; ++k) acc += W0[i * EMBED + k] * Wfc[k * HD + j];
        Wc[tid] = acc;
    } else if (tid < IN_DIM * HD + HD) {
        int j = tid - IN_DIM * HD;
        float acc = 0.f;
        for (int k = 0; k < EMBED; ++k) acc += b0[k] * Wfc[k * HD + j];
        bc[j] = acc;
    }
}

// K1: feat = fp16(feature @ Wc + bc)   (N x 64) @ (64 x 128)
__global__ void __launch_bounds__(256) k1_gemm(const float* __restrict__ A,
                                               const float* __restrict__ W,
                                               const float* __restrict__ b,
                                               __half* __restrict__ out) {
    __shared__ float Ws[IN_DIM * HD];
    __shared__ float As[32][65];
    const int t = threadIdx.x;
    const int c = t & 127, rr = t >> 7;
    const int row0 = blockIdx.x * 32;
    for (int i = t; i < IN_DIM * HD; i += 256) Ws[i] = W[i];
    for (int i = t; i < 32 * IN_DIM; i += 256) {
        int r = i >> 6, k = i & 63;
        int gr = row0 + r;
        As[r][k] = (gr < N_NODES) ? A[(size_t)gr * IN_DIM + k] : 0.f;
    }
    __syncthreads();
    float acc[16];
#pragma unroll
    for (int i = 0; i < 16; ++i) acc[i] = 0.f;
    for (int k = 0; k < IN_DIM; ++k) {
        float w = Ws[k * HD + c];
#pragma unroll
        for (int i = 0; i < 16; ++i) acc[i] += As[rr * 16 + i][k] * w;
    }
    const float bb = b[c];
#pragma unroll
    for (int i = 0; i < 16; ++i) {
        int gr = row0 + rr * 16 + i;
        if (gr < N_NODES) out[(size_t)gr * HD + c] = __float2half(acc[i] + bb);
    }
}

// K2: el/er per node from fp16 feat. One wave per node.
__global__ void __launch_bounds__(256) k2_elr(const __half* __restrict__ feat,
                                              const float* __restrict__ attn_l,
                                              const float* __restrict__ attn_r,
                                              float* __restrict__ el, float* __restrict__ er) {
    const int wid = threadIdx.x >> 6, lane = threadIdx.x & 63;
    const int n = blockIdx.x * 4 + wid;
    if (n >= N_NODES) return;
    const __half2 fh = *(const __half2*)(feat + (size_t)n * HD + lane * 2);
    const float2 f = __half22float2(fh);
    const float2 al = *(const float2*)(attn_l + lane * 2);
    const float2 ar = *(const float2*)(attn_r + lane * 2);
    float pl = f.x * al.x + f.y * al.y;
    float pr = f.x * ar.x + f.y * ar.y;
#pragma unroll
    for (int off = 8; off; off >>= 1) {
        pl += __shfl_xor(pl, off);
        pr += __shfl_xor(pr, off);
    }
    if ((lane & 15) == 0) {
        el[n * 4 + (lane >> 4)] = pl;
        er[n * 4 + (lane >> 4)] = pr;
    }
}

// K3: in-degree count
__global__ void k3_deg(const int* __restrict__ dst, int* __restrict__ deg) {
    int e = blockIdx.x * 256 + threadIdx.x;
    if (e < E_EDGES) atomicAdd(deg + dst[e], 1);
}

// K4a: per-block (256-elem chunk) sums of deg
__global__ void __launch_bounds__(256) k4a_partial(const int* __restrict__ deg,
                                                   int* __restrict__ partial) {
    const int t = threadIdx.x, i = blockIdx.x * 256 + t;
    const int lane = t & 63, wid = t >> 6;
    int v = (i < N_NODES) ? deg[i] : 0;
    int s = v;
#pragma unroll
    for (int off = 32; off; off >>= 1) s += __shfl_xor(s, off);
    __shared__ int ws[4];
    if (lane == 0) ws[wid] = s;
    __syncthreads();
    if (t == 0) partial[blockIdx.x] = ws[0] + ws[1] + ws[2] + ws[3];
}

// K4b: exclusive scan of the 196 partials (single block)
__global__ void __launch_bounds__(256) k4b_scanpart(int* __restrict__ partial) {
    const int t = threadIdx.x, lane = t & 63, wid = t >> 6;
    int v = (t < SCAN_BLOCKS) ? partial[t] : 0;
    int incl = v;
#pragma unroll
    for (int off = 1; off < 64; off <<= 1) {
        int o = __shfl_up(incl, off, 64);
        if (lane >= off) incl += o;
    }
    __shared__ int ws[4];
    if (lane == 63) ws[wid] = incl;
    __syncthreads();
    int base = 0;
    for (int i = 0; i < wid; ++i) base += ws[i];
    if (t < SCAN_BLOCKS) partial[t] = base + incl - v;
}

// K4c: per-block exclusive scan + block offset -> rowstart
__global__ void __launch_bounds__(256) k4c_scan(const int* __restrict__ deg,
                                                const int* __restrict__ partial,
                                                int* __restrict__ rowstart) {
    const int t = threadIdx.x, i = blockIdx.x * 256 + t;
    const int lane = t & 63, wid = t >> 6;
    int v = (i < N_NODES) ? deg[i] : 0;
    int incl = v;
#pragma unroll
    for (int off = 1; off < 64; off <<= 1) {
        int o = __shfl_up(incl, off, 64);
        if (lane >= off) incl += o;
    }
    __shared__ int ws[4];
    if (lane == 63) ws[wid] = incl;
    __syncthreads();
    int base = partial[blockIdx.x];
    for (int w = 0; w < wid; ++w) base += ws[w];
    if (i < N_NODES) rowstart[i] = base + incl - v;
    if (i == 0) rowstart[N_NODES] = E_EDGES;
}

// K5: fill CSR buckets with src
__global__ void k5_fill(const int* __restrict__ src, const int* __restrict__ dst,
                        const int* __restrict__ rowstart, int* __restrict__ cursor,
                        int* __restrict__ csr_src) {
    int e = blockIdx.x * 256 + threadIdx.x;
    if (e < E_EDGES) {
        int d = dst[e];
        int pos = atomicAdd(cursor + d, 1);
        csr_src[rowstart[d] + pos] = src[e];
    }
}

// K6: per-dst softmax stats + message aggregation. One wave per dst.
// Writes per-node (max, 1/denom) to mrd for K6b, and hn = rst + gat_bias.
__global__ void __launch_bounds__(256) k6_aggregate(
    const int* __restrict__ csr_src, const int* __restrict__ rowstart,
    const float* __restrict__ el, const float* __restrict__ er,
    const __half* __restrict__ feat, const float* __restrict__ gat_bias,
    float* __restrict__ mrd, float* __restrict__ hn) {
    const int wid = threadIdx.x >> 6;
    const int lane = threadIdx.x & 63;
    const int n = blockIdx.x * 4 + wid;
    if (n >= N_NODES) return;
    const int start = rowstart[n];
    const int end = rowstart[n + 1];
    const int deg = end - start;
    const float4 er4 = *(const float4*)(er + n * 4);

    // ---- pass 1: per-head max + exp-sum; lane l owns edge start+l (deg<=64 case) ----
    int esrc = 0;
    float4 eh0 = make_float4(0.f, 0.f, 0.f, 0.f);
    const bool valid = lane < deg;
    float4 mx = make_float4(-INFINITY, -INFINITY, -INFINITY, -INFINITY);
    if (valid) {
        esrc = csr_src[start + lane];
        const float4 elv = *(const float4*)(el + esrc * 4);
        eh0.x = leaky(elv.x + er4.x);
        eh0.y = leaky(elv.y + er4.y);
        eh0.z = leaky(elv.z + er4.z);
        eh0.w = leaky(elv.w + er4.w);
        mx = eh0;
    }
    for (int e = start + lane + 64; e < end; e += 64) {  // deg>64: essentially never
        int s = csr_src[e];
        const float4 elv = *(const float4*)(el + s * 4);
        mx.x = fmaxf(mx.x, leaky(elv.x + er4.x));
        mx.y = fmaxf(mx.y, leaky(elv.y + er4.y));
        mx.z = fmaxf(mx.z, leaky(elv.z + er4.z));
        mx.w = fmaxf(mx.w, leaky(elv.w + er4.w));
    }
#pragma unroll
    for (int off = 32; off; off >>= 1) {
        mx.x = fmaxf(mx.x, __shfl_xor(mx.x, off));
        mx.y = fmaxf(mx.y, __shfl_xor(mx.y, off));
        mx.z = fmaxf(mx.z, __shfl_xor(mx.z, off));
        mx.w = fmaxf(mx.w, __shfl_xor(mx.w, off));
    }
    float4 sm = make_float4(0.f, 0.f, 0.f, 0.f);
    if (valid) {
        sm.x = __expf(eh0.x - mx.x);
        sm.y = __expf(eh0.y - mx.y);
        sm.z = __expf(eh0.z - mx.z);
        sm.w = __expf(eh0.w - mx.w);
    }
    for (int e = start + lane + 64; e < end; e += 64) {
        int s = csr_src[e];
        const float4 elv = *(const float4*)(el + s * 4);
        sm.x += __expf(leaky(elv.x + er4.x) - mx.x);
        sm.y += __expf(leaky(elv.y + er4.y) - mx.y);
        sm.z += __expf(leaky(elv.z + er4.z) - mx.z);
        sm.w += __expf(leaky(elv.w + er4.w) - mx.w);
    }
#pragma unroll
    for (int off = 32; off; off >>= 1) {
        sm.x += __shfl_xor(sm.x, off);
        sm.y += __shfl_xor(sm.y, off);
        sm.z += __shfl_xor(sm.z, off);
        sm.w += __shfl_xor(sm.w, off);
    }
    float4 rd;
    rd.x = sm.x > 0.f ? 1.f / sm.x : 0.f;
    rd.y = sm.y > 0.f ? 1.f / sm.y : 0.f;
    rd.z = sm.z > 0.f ? 1.f / sm.z : 0.f;
    rd.w = sm.w > 0.f ? 1.f / sm.w : 0.f;
    if (lane == 0) {
        ((float4*)mrd)[(size_t)n * 2] = mx;
        ((float4*)mrd)[(size_t)n * 2 + 1] = rd;
    }

    // ---- pass 2: 16 lanes per edge (16B fp16 each = 8 channels, one head per lane) ----
    const int g4 = lane >> 4, gl = lane & 15;
    const int h = gl >> 2;                       // head for channels [gl*8, gl*8+8)
    const float mh = compf(mx, h), rh = compf(rd, h);
    const float erh = compf(er4, h);
    float4 a0 = make_float4(0.f, 0.f, 0.f, 0.f); // channels gl*8 .. +3
    float4 a1 = make_float4(0.f, 0.f, 0.f, 0.f); // channels gl*8+4 .. +7

    if (deg <= 64) {
        // uniform trip count: ALL lanes iterate together -> shfl always well-defined
        const int iters = (deg + 3) >> 2;
        int idx = g4;
        for (int it = 0; it < iters; ++it, idx += 4) {
            const bool act = idx < deg;
            const int sidx = act ? idx : 0;
            const int cs = __shfl(esrc, sidx);
            const float e0 = __shfl(eh0.x, sidx);
            const float e1 = __shfl(eh0.y, sidx);
            const float e2 = __shfl(eh0.z, sidx);
            const float e3 = __shfl(eh0.w, sidx);
            const float4 raw = ((const float4*)(feat + (size_t)cs * HD))[gl];
            const float eh = compf(make_float4(e0, e1, e2, e3), h);
            const float av = act ? __expf(eh - mh) * rh : 0.f;
            const __half2* hp = (const __half2*)&raw;
            const float2 p0 = __half22float2(hp[0]);
            const float2 p1 = __half22float2(hp[1]);
            const float2 p2 = __half22float2(hp[2]);
            const float2 p3 = __half22float2(hp[3]);
            a0.x += av * p0.x; a0.y += av * p0.y;
            a0.z += av * p1.x; a0.w += av * p1.y;
            a1.x += av * p2.x; a1.y += av * p2.y;
            a1.z += av * p3.x; a1.w += av * p3.y;
        }
    } else {
        for (int e = start + g4; e < end; e += 4) {
            const int s = csr_src[e];
            const float eh = leaky(el[s * 4 + h] + erh);
            const float av = __expf(eh - mh) * rh;
            const float4 raw = ((const float4*)(feat + (size_t)s * HD))[gl];
            const __half2* hp = (const __half2*)&raw;
            const float2 p0 = __half22float2(hp[0]);
            const float2 p1 = __half22float2(hp[1]);
            const float2 p2 = __half22float2(hp[2]);
            const float2 p3 = __half22float2(hp[3]);
            a0.x += av * p0.x; a0.y += av * p0.y;
            a0.z += av * p1.x; a0.w += av * p1.y;
            a1.x += av * p2.x; a1.y += av * p2.y;
            a1.z += av * p3.x; a1.w += av * p3.y;
        }
    }
#pragma unroll
    for (int off = 16; off <= 32; off <<= 1) {
        a0.x += __shfl_xor(a0.x, off);
        a0.y += __shfl_xor(a0.y, off);
        a0.z += __shfl_xor(a0.z, off);
        a0.w += __shfl_xor(a0.w, off);
        a1.x += __shfl_xor(a1.x, off);
        a1.y += __shfl_xor(a1.y, off);
        a1.z += __shfl_xor(a1.z, off);
        a1.w += __shfl_xor(a1.w, off);
    }
    if (lane < 16) {
        const float4 b0 = ((const float4*)gat_bias)[gl * 2];
        const float4 b1 = ((const float4*)gat_bias)[gl * 2 + 1];
        float4* hp = (float4*)(hn + (size_t)n * HD + gl * 8);
        hp[0] = make_float4(a0.x + b0.x, a0.y + b0.y, a0.z + b0.z, a0.w + b0.w);
        hp[1] = make_float4(a1.x + b1.x, a1.y + b1.y, a1.z + b1.z, a1.w + b1.w);
    }
}

// K6b: attention coefficients in edge order (coalesced nontemporal writes)
__global__ void __launch_bounds__(256) k6b_attn(
    const int* __restrict__ src, const int* __restrict__ dst,
    const float* __restrict__ el, const float* __restrict__ er,
    const float* __restrict__ mrd, float* __restrict__ a_out) {
    int e = blockIdx.x * 256 + threadIdx.x;
    if (e >= E_EDGES) return;
    const int s = src[e], d = dst[e];
    const float4 el4 = *(const float4*)(el + s * 4);
    const float4 er4 = *(const float4*)(er + d * 4);
    const float4 m4 = ((const float4*)mrd)[(size_t)d * 2];
    const float4 r4 = ((const float4*)mrd)[(size_t)d * 2 + 1];
    vfloat4 a;
    a.x = __expf(leaky(el4.x + er4.x) - m4.x) * r4.x;
    a.y = __expf(leaky(el4.y + er4.y) - m4.y) * r4.y;
    a.z = __expf(leaky(el4.z + er4.z) - m4.z) * r4.z;
    a.w = __expf(leaky(el4.w + er4.w) - m4.w) * r4.w;
    __builtin_nontemporal_store(a, (vfloat4*)a_out + e);
}

// K7: deterministic f64 mean-pool (graph_ids sorted -> contiguous ranges) + f64 MLP.
__global__ void __launch_bounds__(512) k7_pool_mlp(
    const float* __restrict__ hn, const int* __restrict__ graph_ids,
    const float* __restrict__ W1, const float* __restrict__ b1,
    const float* __restrict__ W2, const float* __restrict__ b2,
    const float* __restrict__ W3, const float* __restrict__ b3,
    float* __restrict__ out) {
    const int g = blockIdx.x, t = threadIdx.x;
    const int tt = t & 127, part = t >> 7;
    __shared__ int bounds[2];
    __shared__ double pool[4][128];
    __shared__ double x[128], y[128];
    if (t < 2) {
        const int target = g + t;
        int lo = 0, hi = N_NODES;
        while (lo < hi) {
            int mid = (lo + hi) >> 1;
            if (graph_ids[mid] < target) lo = mid + 1; else hi = mid;
        }
        bounds[t] = lo;
    }
    __syncthreads();
    const int lo = bounds[0], hi = bounds[1];
    double s = 0.0;
    for (int n = lo + part; n < hi; n += 4) s += (double)hn[(size_t)n * HD + tt];
    pool[part][tt] = s;
    __syncthreads();
    if (t < 128) {
        const double cnt = (double)(hi - lo);
        const double sum = pool[0][t] + pool[1][t] + pool[2][t] + pool[3][t];
        const double v = sum / fmax(cnt, 1.0);
        x[t] = v > 0.0 ? v : expm1(v);
    }
    __syncthreads();
    if (t < 128) {
        double acc = (double)b1[t];
        for (int k = 0; k < HD; ++k) acc += x[k] * (double)W1[k * D1 + t];
        y[t] = acc > 0.0 ? acc : expm1(acc);
    }
    __syncthreads();
    if (t < D2) {
        double a2 = (double)b2[t];
        for (int k = 0; k < D1; ++k) a2 += y[k] * (double)W2[k * D2 + t];
        x[t] = a2 > 0.0 ? a2 : expm1(a2);
    }
    __syncthreads();
    if (t < D3) {
        double a3 = (double)b3[t];
        for (int k = 0; k < D2; ++k) a3 += x[k] * (double)W3[k * D3 + t];
        out[g * D3 + t] = (float)a3;
    }
}

extern "C" void kernel_launch(void* const* d_in, const int* in_sizes, int n_in,
                              void* d_out, int out_size, void* d_ws, size_t ws_size,
                              hipStream_t stream) {
    const float* feature = (const float*)d_in[0];
    const int* src = (const int*)d_in[1];
    const int* dst = (const int*)d_in[2];
    const int* graph_ids = (const int*)d_in[3];
    const float* W0 = (const float*)d_in[4];
    const float* b0 = (const float*)d_in[5];
    const float* Wfc = (const float*)d_in[6];
    const float* attn_l = (const float*)d_in[7];
    const float* attn_r = (const float*)d_in[8];
    const float* gat_bias = (const float*)d_in[9];
    const float* W1 = (const float*)d_in[10];
    const float* b1 = (const float*)d_in[11];
    const float* W2 = (const float*)d_in[12];
    const float* b2 = (const float*)d_in[13];
    const float* W3 = (const float*)d_in[14];
    const float* b3 = (const float*)d_in[15];

    char* ws = (char*)d_ws;
    size_t off = 0;
    auto carve = [&](size_t bytes) -> void* {
        void* p = ws + off;
        off += (bytes + 255) & ~(size_t)255;
        return p;
    };
    // zero-initialized region first (single memset)
    int* deg = (int*)carve((size_t)N_NODES * 4);
    int* cursor = (int*)carve((size_t)N_NODES * 4);
    const size_t zero_span = off;
    float* Wc = (float*)carve((size_t)IN_DIM * HD * 4);
    float* bc = (float*)carve((size_t)HD * 4);
    __half* feat = (__half*)carve((size_t)N_NODES * HD * 2);
    float* el = (float*)carve((size_t)N_NODES * 4 * 4);
    float* er = (float*)carve((size_t)N_NODES * 4 * 4);
    int* rowstart = (int*)carve((size_t)(N_NODES + 1) * 4);
    int* partial = (int*)carve((size_t)SCAN_BLOCKS * 4);
    int* csr_src = (int*)carve((size_t)E_EDGES * 4);
    float* mrd = (float*)carve((size_t)N_NODES * 8 * 4);

    float* out = (float*)d_out;
    // atten region of d_out doubles as hn scratch: K6 writes hn, K7 reads it,
    // THEN K6b overwrites the region with the final attention output.
    // (N*HD == E*NHEAD == 6.4M floats exactly.)
    float* hn = out + G_GRAPHS * D3;
    float* a_out = hn;

    (void)hipMemsetAsync(d_ws, 0, zero_span, stream);
    k0_compose<<<(IN_DIM * HD + HD + 255) / 256, 256, 0, stream>>>(W0, b0, Wfc, Wc, bc);
    k1_gemm<<<(N_NODES + 31) / 32, 256, 0, stream>>>(feature, Wc, bc, feat);
    k2_elr<<<(N_NODES + 3) / 4, 256, 0, stream>>>(feat, attn_l, attn_r, el, er);
    k3_deg<<<(E_EDGES + 255) / 256, 256, 0, stream>>>(dst, deg);
    k4a_partial<<<SCAN_BLOCKS, 256, 0, stream>>>(deg, partial);
    k4b_scanpart<<<1, 256, 0, stream>>>(partial);
    k4c_scan<<<SCAN_BLOCKS, 256, 0, stream>>>(deg, partial, rowstart);
    k5_fill<<<(E_EDGES + 255) / 256, 256, 0, stream>>>(src, dst, rowstart, cursor, csr_src);
    k6_aggregate<<<(N_NODES + 3) / 4, 256, 0, stream>>>(csr_src, rowstart, el, er, feat,
                                                        gat_bias, mrd, hn);
    k7_pool_mlp<<<G_GRAPHS, 512, 0, stream>>>(hn, graph_ids, W1, b1, W2, b2, W3, b3, out);
    k6b_attn<<<(E_EDGES + 255) / 256, 256, 0, stream>>>(src, dst, el, er, mrd, a_out);
}

// Round 6
// 304.849 us; speedup vs baseline: 2.1841x; 1.3667x over previous
//
#include <hip/hip_runtime.h>
#include <hip/hip_fp16.h>
#include <math.h>

#define N_NODES 50000
#define E_EDGES 1600000
#define G_GRAPHS 512
#define IN_DIM 64
#define EMBED 128
#define HD 128
#define NHEAD 4
#define D1 128
#define D2 64
#define D3 16
#define NEG_SLOPE 0.2f
#define NB ((N_NODES + 127) >> 7)                       // 391 coarse buckets (128 nodes each)
#define PT_TILE 4096
#define PT_BLOCKS ((E_EDGES + PT_TILE - 1) / PT_TILE)   // 391
#define FB_CAP 8192

typedef float vfloat4 __attribute__((ext_vector_type(4)));

static __device__ __forceinline__ float leaky(float x) { return x > 0.f ? x : NEG_SLOPE * x; }
static __device__ __forceinline__ float compf(float4 v, int i) {
    return i == 0 ? v.x : (i == 1 ? v.y : (i == 2 ? v.z : v.w));
}

// K0: Wcomb = W0 @ Wfc (64x128), bcomb = b0 @ Wfc (128)
__global__ void k0_compose(const float* __restrict__ W0, const float* __restrict__ b0,
                           const float* __restrict__ Wfc, float* __restrict__ Wc,
                           float* __restrict__ bc) {
    int tid = blockIdx.x * blockDim.x + threadIdx.x;
    if (tid < IN_DIM * HD) {
        int i = tid >> 7, j = tid & 127;
        float acc = 0.f;
        for (int k = 0; k < EMBED; ++k) acc += W0[i * EMBED + k] * Wfc[k * HD + j];
        Wc[tid] = acc;
    } else if (tid < IN_DIM * HD + HD) {
        int j = tid - IN_DIM * HD;
        float acc = 0.f;
        for (int k = 0; k < EMBED; ++k) acc += b0[k] * Wfc[k * HD + j];
        bc[j] = acc;
    }
}

// K1: feat = fp16(feature @ Wc + bc)   (N x 64) @ (64 x 128)
__global__ void __launch_bounds__(256) k1_gemm(const float* __restrict__ A,
                                               const float* __restrict__ W,
                                               const float* __restrict__ b,
                                               __half* __restrict__ out) {
    __shared__ float Ws[IN_DIM * HD];
    __shared__ float As[32][65];
    const int t = threadIdx.x;
    const int c = t & 127, rr = t >> 7;
    const int row0 = blockIdx.x * 32;
    for (int i = t; i < IN_DIM * HD; i += 256) Ws[i] = W[i];
    for (int i = t; i < 32 * IN_DIM; i += 256) {
        int r = i >> 6, k = i & 63;
        int gr = row0 + r;
        As[r][k] = (gr < N_NODES) ? A[(size_t)gr * IN_DIM + k] : 0.f;
    }
    __syncthreads();
    float acc[16];
#pragma unroll
    for (int i = 0; i < 16; ++i) acc[i] = 0.f;
    for (int k = 0; k < IN_DIM; ++k) {
        float w = Ws[k * HD + c];
#pragma unroll
        for (int i = 0; i < 16; ++i) acc[i] += As[rr * 16 + i][k] * w;
    }
    const float bb = b[c];
#pragma unroll
    for (int i = 0; i < 16; ++i) {
        int gr = row0 + rr * 16 + i;
        if (gr < N_NODES) out[(size_t)gr * HD + c] = __float2half(acc[i] + bb);
    }
}

// K2: el/er per node from fp16 feat. One wave per node.
__global__ void __launch_bounds__(256) k2_elr(const __half* __restrict__ feat,
                                              const float* __restrict__ attn_l,
                                              const float* __restrict__ attn_r,
                                              float* __restrict__ el, float* __restrict__ er) {
    const int wid = threadIdx.x >> 6, lane = threadIdx.x & 63;
    const int n = blockIdx.x * 4 + wid;
    if (n >= N_NODES) return;
    const __half2 fh = *(const __half2*)(feat + (size_t)n * HD + lane * 2);
    const float2 f = __half22float2(fh);
    const float2 al = *(const float2*)(attn_l + lane * 2);
    const float2 ar = *(const float2*)(attn_r + lane * 2);
    float pl = f.x * al.x + f.y * al.y;
    float pr = f.x * ar.x + f.y * ar.y;
#pragma unroll
    for (int off = 8; off; off >>= 1) {
        pl += __shfl_xor(pl, off);
        pr += __shfl_xor(pr, off);
    }
    if ((lane & 15) == 0) {
        el[n * 4 + (lane >> 4)] = pl;
        er[n * 4 + (lane >> 4)] = pr;
    }
}

// HG: coarse histogram of dst>>7 (LDS-staged)
__global__ void __launch_bounds__(256) hg_hist(const int* __restrict__ dst,
                                               int* __restrict__ ghist) {
    __shared__ int lh[NB];
    const int t = threadIdx.x;
    for (int i = t; i < NB; i += 256) lh[i] = 0;
    __syncthreads();
    const long e0 = (long)blockIdx.x * PT_TILE;
#pragma unroll
    for (int k = 0; k < PT_TILE / 256; ++k) {
        long e = e0 + t + k * 256;
        if (e < E_EDGES) atomicAdd(&lh[dst[e] >> 7], 1);
    }
    __syncthreads();
    for (int i = t; i < NB; i += 256) {
        int v = lh[i];
        if (v) atomicAdd(&ghist[i], v);
    }
}

// SC: exclusive scan of NB coarse counts -> coarse_start + cursor (one wave)
__global__ void __launch_bounds__(64) sc_scan(const int* __restrict__ ghist,
                                              int* __restrict__ coarse_start,
                                              int* __restrict__ cursorp) {
    const int lane = threadIdx.x;
    int run = 0;
    for (int c = 0; c < (NB + 63) / 64; ++c) {
        int i = c * 64 + lane;
        int v = (i < NB) ? ghist[i] : 0;
        int incl = v;
#pragma unroll
        for (int off = 1; off < 64; off <<= 1) {
            int o = __shfl_up(incl, off, 64);
            if (lane >= off) incl += o;
        }
        if (i < NB) {
            coarse_start[i] = run + incl - v;
            cursorp[i] = run + incl - v;
        }
        run += __shfl(incl, 63, 64);
    }
    if (lane == 0) coarse_start[NB] = E_EDGES;
}

// PT: partition edges into coarse buckets with LDS reorder -> coalesced flush
__global__ void __launch_bounds__(256) pt_partition(const int* __restrict__ src,
                                                    const int* __restrict__ dst,
                                                    int* __restrict__ cursorp,
                                                    int2* __restrict__ part) {
    __shared__ int hist[NB], offs[NB], lcur[NB], base_s[NB];
    __shared__ int2 stage[PT_TILE];
    const int t = threadIdx.x, lane = t & 63, wid = t >> 6;
    const long e0 = (long)blockIdx.x * PT_TILE;
    const int cnt = (int)min((long)PT_TILE, (long)E_EDGES - e0);
    for (int i = t; i < NB; i += 256) hist[i] = 0;
    __syncthreads();
    int dv[PT_TILE / 256], sv[PT_TILE / 256];
#pragma unroll
    for (int k = 0; k < PT_TILE / 256; ++k) {
        int i = t + k * 256;
        if (i < cnt) {
            dv[k] = dst[e0 + i];
            sv[k] = src[e0 + i];
            atomicAdd(&hist[dv[k] >> 7], 1);
        } else dv[k] = -1;
    }
    __syncthreads();
    if (wid == 0) {
        int run = 0;
        for (int c = 0; c < (NB + 63) / 64; ++c) {
            int i = c * 64 + lane;
            int v = (i < NB) ? hist[i] : 0;
            int incl = v;
#pragma unroll
            for (int off = 1; off < 64; off <<= 1) {
                int o = __shfl_up(incl, off, 64);
                if (lane >= off) incl += o;
            }
            if (i < NB) offs[i] = run + incl - v;
            run += __shfl(incl, 63, 64);
        }
    }
    __syncthreads();
    for (int i = t; i < NB; i += 256) {
        lcur[i] = offs[i];
        int h = hist[i];
        base_s[i] = h ? atomicAdd(&cursorp[i], h) : 0;
    }
    __syncthreads();
#pragma unroll
    for (int k = 0; k < PT_TILE / 256; ++k) {
        if (dv[k] >= 0) {
            int b = dv[k] >> 7;
            int pos = atomicAdd(&lcur[b], 1);
            stage[pos] = make_int2(dv[k], sv[k]);
        }
    }
    __syncthreads();
    for (int i = t; i < cnt; i += 256) {
        int2 p = stage[i];
        int b = p.x >> 7;
        part[base_s[b] + (i - offs[b])] = p;
    }
}

// FB: per-bucket fine fill: local deg/scan -> rowstart, LDS place -> coalesced csr_src
__global__ void __launch_bounds__(256) fb_fill(const int2* __restrict__ part,
                                               const int* __restrict__ coarse_start,
                                               int* __restrict__ rowstart,
                                               int* __restrict__ csr_src) {
    const int b = blockIdx.x, t = threadIdx.x, lane = t & 63, wid = t >> 6;
    const int s0 = coarse_start[b], s1 = coarse_start[b + 1];
    const int cnt = s1 - s0;
    __shared__ int degl[128], offl[128], curl[128];
    __shared__ int lsrc[FB_CAP];
    if (t < 128) degl[t] = 0;
    __syncthreads();
    for (int i = t; i < cnt; i += 256) {
        int2 p = part[s0 + i];
        atomicAdd(&degl[p.x & 127], 1);
    }
    __syncthreads();
    if (wid == 0) {
        int run = 0;
        for (int c = 0; c < 2; ++c) {
            int i = c * 64 + lane;
            int v = degl[i];
            int incl = v;
#pragma unroll
            for (int off = 1; off < 64; off <<= 1) {
                int o = __shfl_up(incl, off, 64);
                if (lane >= off) incl += o;
            }
            offl[i] = run + incl - v;
            run += __shfl(incl, 63, 64);
        }
    }
    __syncthreads();
    if (t < 128) {
        curl[t] = offl[t];
        int node = b * 128 + t;
        if (node < N_NODES) rowstart[node] = s0 + offl[t];
    }
    if (b == 0 && t == 0) rowstart[N_NODES] = E_EDGES;
    __syncthreads();
    if (cnt <= FB_CAP) {
        for (int i = t; i < cnt; i += 256) {
            int2 p = part[s0 + i];
            int pos = atomicAdd(&curl[p.x & 127], 1);
            lsrc[pos] = p.y;
        }
        __syncthreads();
        for (int i = t; i < cnt; i += 256) csr_src[s0 + i] = lsrc[i];
    } else {
        for (int i = t; i < cnt; i += 256) {
            int2 p = part[s0 + i];
            int pos = atomicAdd(&curl[p.x & 127], 1);
            csr_src[s0 + pos] = p.y;
        }
    }
}

// K6: per-dst softmax stats + message aggregation. One wave per dst.
__global__ void __launch_bounds__(256) k6_aggregate(
    const int* __restrict__ csr_src, const int* __restrict__ rowstart,
    const float* __restrict__ el, const float* __restrict__ er,
    const __half* __restrict__ feat, const float* __restrict__ gat_bias,
    float* __restrict__ mrd, float* __restrict__ hn) {
    const int wid = threadIdx.x >> 6;
    const int lane = threadIdx.x & 63;
    const int n = blockIdx.x * 4 + wid;
    if (n >= N_NODES) return;
    const int start = rowstart[n];
    const int end = rowstart[n + 1];
    const int deg = end - start;
    const float4 er4 = *(const float4*)(er + n * 4);

    // ---- pass 1: per-head max + exp-sum; lane l owns edge start+l (deg<=64 case) ----
    int esrc = 0;
    float4 eh0 = make_float4(0.f, 0.f, 0.f, 0.f);
    const bool valid = lane < deg;
    float4 mx = make_float4(-INFINITY, -INFINITY, -INFINITY, -INFINITY);
    if (valid) {
        esrc = csr_src[start + lane];
        const float4 elv = *(const float4*)(el + esrc * 4);
        eh0.x = leaky(elv.x + er4.x);
        eh0.y = leaky(elv.y + er4.y);
        eh0.z = leaky(elv.z + er4.z);
        eh0.w = leaky(elv.w + er4.w);
        mx = eh0;
    }
    for (int e = start + lane + 64; e < end; e += 64) {  // deg>64: essentially never
        int s = csr_src[e];
        const float4 elv = *(const float4*)(el + s * 4);
        mx.x = fmaxf(mx.x, leaky(elv.x + er4.x));
        mx.y = fmaxf(mx.y, leaky(elv.y + er4.y));
        mx.z = fmaxf(mx.z, leaky(elv.z + er4.z));
        mx.w = fmaxf(mx.w, leaky(elv.w + er4.w));
    }
#pragma unroll
    for (int off = 32; off; off >>= 1) {
        mx.x = fmaxf(mx.x, __shfl_xor(mx.x, off));
        mx.y = fmaxf(mx.y, __shfl_xor(mx.y, off));
        mx.z = fmaxf(mx.z, __shfl_xor(mx.z, off));
        mx.w = fmaxf(mx.w, __shfl_xor(mx.w, off));
    }
    float4 sm = make_float4(0.f, 0.f, 0.f, 0.f);
    if (valid) {
        sm.x = __expf(eh0.x - mx.x);
        sm.y = __expf(eh0.y - mx.y);
        sm.z = __expf(eh0.z - mx.z);
        sm.w = __expf(eh0.w - mx.w);
    }
    for (int e = start + lane + 64; e < end; e += 64) {
        int s = csr_src[e];
        const float4 elv = *(const float4*)(el + s * 4);
        sm.x += __expf(leaky(elv.x + er4.x) - mx.x);
        sm.y += __expf(leaky(elv.y + er4.y) - mx.y);
        sm.z += __expf(leaky(elv.z + er4.z) - mx.z);
        sm.w += __expf(leaky(elv.w + er4.w) - mx.w);
    }
#pragma unroll
    for (int off = 32; off; off >>= 1) {
        sm.x += __shfl_xor(sm.x, off);
        sm.y += __shfl_xor(sm.y, off);
        sm.z += __shfl_xor(sm.z, off);
        sm.w += __shfl_xor(sm.w, off);
    }
    float4 rd;
    rd.x = sm.x > 0.f ? 1.f / sm.x : 0.f;
    rd.y = sm.y > 0.f ? 1.f / sm.y : 0.f;
    rd.z = sm.z > 0.f ? 1.f / sm.z : 0.f;
    rd.w = sm.w > 0.f ? 1.f / sm.w : 0.f;
    if (lane == 0) {
        ((float4*)mrd)[(size_t)n * 2] = mx;
        ((float4*)mrd)[(size_t)n * 2 + 1] = rd;
    }

    // ---- pass 2: 16 lanes per edge (16B fp16 each = 8 channels, one head per lane) ----
    const int g4 = lane >> 4, gl = lane & 15;
    const int h = gl >> 2;                       // head for channels [gl*8, gl*8+8)
    const float mh = compf(mx, h), rh = compf(rd, h);
    const float erh = compf(er4, h);
    float4 a0 = make_float4(0.f, 0.f, 0.f, 0.f); // channels gl*8 .. +3
    float4 a1 = make_float4(0.f, 0.f, 0.f, 0.f); // channels gl*8+4 .. +7

    if (deg <= 64) {
        // uniform trip count: ALL lanes iterate together -> shfl always well-defined
        const int iters = (deg + 3) >> 2;
        int idx = g4;
        for (int it = 0; it < iters; ++it, idx += 4) {
            const bool act = idx < deg;
            const int sidx = act ? idx : 0;
            const int cs = __shfl(esrc, sidx);
            const float e0 = __shfl(eh0.x, sidx);
            const float e1 = __shfl(eh0.y, sidx);
            const float e2 = __shfl(eh0.z, sidx);
            const float e3 = __shfl(eh0.w, sidx);
            const float4 raw = ((const float4*)(feat + (size_t)cs * HD))[gl];
            const float eh = compf(make_float4(e0, e1, e2, e3), h);
            const float av = act ? __expf(eh - mh) * rh : 0.f;
            const __half2* hp = (const __half2*)&raw;
            const float2 p0 = __half22float2(hp[0]);
            const float2 p1 = __half22float2(hp[1]);
            const float2 p2 = __half22float2(hp[2]);
            const float2 p3 = __half22float2(hp[3]);
            a0.x += av * p0.x; a0.y += av * p0.y;
            a0.z += av * p1.x; a0.w += av * p1.y;
            a1.x += av * p2.x; a1.y += av * p2.y;
            a1.z += av * p3.x; a1.w += av * p3.y;
        }
    } else {
        for (int e = start + g4; e < end; e += 4) {
            const int s = csr_src[e];
            const float eh = leaky(el[s * 4 + h] + erh);
            const float av = __expf(eh - mh) * rh;
            const float4 raw = ((const float4*)(feat + (size_t)s * HD))[gl];
            const __half2* hp = (const __half2*)&raw;
            const float2 p0 = __half22float2(hp[0]);
            const float2 p1 = __half22float2(hp[1]);
            const float2 p2 = __half22float2(hp[2]);
            const float2 p3 = __half22float2(hp[3]);
            a0.x += av * p0.x; a0.y += av * p0.y;
            a0.z += av * p1.x; a0.w += av * p1.y;
            a1.x += av * p2.x; a1.y += av * p2.y;
            a1.z += av * p3.x; a1.w += av * p3.y;
        }
    }
#pragma unroll
    for (int off = 16; off <= 32; off <<= 1) {
        a0.x += __shfl_xor(a0.x, off);
        a0.y += __shfl_xor(a0.y, off);
        a0.z += __shfl_xor(a0.z, off);
        a0.w += __shfl_xor(a0.w, off);
        a1.x += __shfl_xor(a1.x, off);
        a1.y += __shfl_xor(a1.y, off);
        a1.z += __shfl_xor(a1.z, off);
        a1.w += __shfl_xor(a1.w, off);
    }
    if (lane < 16) {
        const float4 b0 = ((const float4*)gat_bias)[gl * 2];
        const float4 b1 = ((const float4*)gat_bias)[gl * 2 + 1];
        float4* hp = (float4*)(hn + (size_t)n * HD + gl * 8);
        hp[0] = make_float4(a0.x + b0.x, a0.y + b0.y, a0.z + b0.z, a0.w + b0.w);
        hp[1] = make_float4(a1.x + b1.x, a1.y + b1.y, a1.z + b1.z, a1.w + b1.w);
    }
}

// K6b: attention coefficients in edge order (coalesced nontemporal writes)
__global__ void __launch_bounds__(256) k6b_attn(
    const int* __restrict__ src, const int* __restrict__ dst,
    const float* __restrict__ el, const float* __restrict__ er,
    const float* __restrict__ mrd, float* __restrict__ a_out) {
    int e = blockIdx.x * 256 + threadIdx.x;
    if (e >= E_EDGES) return;
    const int s = src[e], d = dst[e];
    const float4 el4 = *(const float4*)(el + s * 4);
    const float4 er4 = *(const float4*)(er + d * 4);
    const float4 m4 = ((const float4*)mrd)[(size_t)d * 2];
    const float4 r4 = ((const float4*)mrd)[(size_t)d * 2 + 1];
    vfloat4 a;
    a.x = __expf(leaky(el4.x + er4.x) - m4.x) * r4.x;
    a.y = __expf(leaky(el4.y + er4.y) - m4.y) * r4.y;
    a.z = __expf(leaky(el4.z + er4.z) - m4.z) * r4.z;
    a.w = __expf(leaky(el4.w + er4.w) - m4.w) * r4.w;
    __builtin_nontemporal_store(a, (vfloat4*)a_out + e);
}

// K7: deterministic f64 mean-pool (graph_ids sorted -> contiguous ranges) + f64 MLP.
__global__ void __launch_bounds__(512) k7_pool_mlp(
    const float* __restrict__ hn, const int* __restrict__ graph_ids,
    const float* __restrict__ W1, const float* __restrict__ b1,
    const float* __restrict__ W2, const float* __restrict__ b2,
    const float* __restrict__ W3, const float* __restrict__ b3,
    float* __restrict__ out) {
    const int g = blockIdx.x, t = threadIdx.x;
    const int tt = t & 127, part = t >> 7;
    __shared__ int bounds[2];
    __shared__ double pool[4][128];
    __shared__ double x[128], y[128];
    if (t < 2) {
        const int target = g + t;
        int lo = 0, hi = N_NODES;
        while (lo < hi) {
            int mid = (lo + hi) >> 1;
            if (graph_ids[mid] < target) lo = mid + 1; else hi = mid;
        }
        bounds[t] = lo;
    }
    __syncthreads();
    const int lo = bounds[0], hi = bounds[1];
    double s = 0.0;
    for (int n = lo + part; n < hi; n += 4) s += (double)hn[(size_t)n * HD + tt];
    pool[part][tt] = s;
    __syncthreads();
    if (t < 128) {
        const double cnt = (double)(hi - lo);
        const double sum = pool[0][t] + pool[1][t] + pool[2][t] + pool[3][t];
        const double v = sum / fmax(cnt, 1.0);
        x[t] = v > 0.0 ? v : expm1(v);
    }
    __syncthreads();
    if (t < 128) {
        double acc = (double)b1[t];
        for (int k = 0; k < HD; ++k) acc += x[k] * (double)W1[k * D1 + t];
        y[t] = acc > 0.0 ? acc : expm1(acc);
    }
    __syncthreads();
    if (t < D2) {
        double a2 = (double)b2[t];
        for (int k = 0; k < D1; ++k) a2 += y[k] * (double)W2[k * D2 + t];
        x[t] = a2 > 0.0 ? a2 : expm1(a2);
    }
    __syncthreads();
    if (t < D3) {
        double a3 = (double)b3[t];
        for (int k = 0; k < D2; ++k) a3 += x[k] * (double)W3[k * D3 + t];
        out[g * D3 + t] = (float)a3;
    }
}

extern "C" void kernel_launch(void* const* d_in, const int* in_sizes, int n_in,
                              void* d_out, int out_size, void* d_ws, size_t ws_size,
                              hipStream_t stream) {
    const float* feature = (const float*)d_in[0];
    const int* src = (const int*)d_in[1];
    const int* dst = (const int*)d_in[2];
    const int* graph_ids = (const int*)d_in[3];
    const float* W0 = (const float*)d_in[4];
    const float* b0 = (const float*)d_in[5];
    const float* Wfc = (const float*)d_in[6];
    const float* attn_l = (const float*)d_in[7];
    const float* attn_r = (const float*)d_in[8];
    const float* gat_bias = (const float*)d_in[9];
    const float* W1 = (const float*)d_in[10];
    const float* b1 = (const float*)d_in[11];
    const float* W2 = (const float*)d_in[12];
    const float* b2 = (const float*)d_in[13];
    const float* W3 = (const float*)d_in[14];
    const float* b3 = (const float*)d_in[15];

    char* ws = (char*)d_ws;
    size_t off = 0;
    auto carve = [&](size_t bytes) -> void* {
        void* p = ws + off;
        off += (bytes + 255) & ~(size_t)255;
        return p;
    };
    // zero-initialized region first (single small memset)
    int* ghist = (int*)carve((size_t)NB * 4);
    const size_t zero_span = off;
    int* coarse_start = (int*)carve((size_t)(NB + 1) * 4);
    int* cursorp = (int*)carve((size_t)NB * 4);
    float* Wc = (float*)carve((size_t)IN_DIM * HD * 4);
    float* bc = (float*)carve((size_t)HD * 4);
    __half* feat = (__half*)carve((size_t)N_NODES * HD * 2);
    float* el = (float*)carve((size_t)N_NODES * 4 * 4);
    float* er = (float*)carve((size_t)N_NODES * 4 * 4);
    int* rowstart = (int*)carve((size_t)(N_NODES + 1) * 4);
    int2* part = (int2*)carve((size_t)E_EDGES * 8);
    int* csr_src = (int*)carve((size_t)E_EDGES * 4);
    float* mrd = (float*)carve((size_t)N_NODES * 8 * 4);

    float* out = (float*)d_out;
    // atten region of d_out doubles as hn scratch: K6 writes hn, K7 reads it,
    // THEN K6b overwrites the region with the final attention output.
    // (N*HD == E*NHEAD == 6.4M floats exactly.)
    float* hn = out + G_GRAPHS * D3;
    float* a_out = hn;

    (void)hipMemsetAsync(d_ws, 0, zero_span, stream);
    k0_compose<<<(IN_DIM * HD + HD + 255) / 256, 256, 0, stream>>>(W0, b0, Wfc, Wc, bc);
    k1_gemm<<<(N_NODES + 31) / 32, 256, 0, stream>>>(feature, Wc, bc, feat);
    k2_elr<<<(N_NODES + 3) / 4, 256, 0, stream>>>(feat, attn_l, attn_r, el, er);
    hg_hist<<<PT_BLOCKS, 256, 0, stream>>>(dst, ghist);
    sc_scan<<<1, 64, 0, stream>>>(ghist, coarse_start, cursorp);
    pt_partition<<<PT_BLOCKS, 256, 0, stream>>>(src, dst, cursorp, part);
    fb_fill<<<NB, 256, 0, stream>>>(part, coarse_start, rowstart, csr_src);
    k6_aggregate<<<(N_NODES + 3) / 4, 256, 0, stream>>>(csr_src, rowstart, el, er, feat,
                                                        gat_bias, mrd, hn);
    k7_pool_mlp<<<G_GRAPHS, 512, 0, stream>>>(hn, graph_ids, W1, b1, W2, b2, W3, b3, out);
    k6b_attn<<<(E_EDGES + 255) / 256, 256, 0, stream>>>(src, dst, el, er, mrd, a_out);
}

// Round 7
// 290.425 us; speedup vs baseline: 2.2925x; 1.0497x over previous
//
#include <hip/hip_runtime.h>
#include <hip/hip_fp16.h>
#include <math.h>

#define N_NODES 50000
#define E_EDGES 1600000
#define G_GRAPHS 512
#define IN_DIM 64
#define EMBED 128
#define HD 128
#define NHEAD 4
#define D1 128
#define D2 64
#define D3 16
#define NEG_SLOPE 0.2f
#define NB ((N_NODES + 127) >> 7)                       // 391 coarse buckets (128 nodes each)
#define PT_TILE 4096
#define PT_BLOCKS ((E_EDGES + PT_TILE - 1) / PT_TILE)   // 391
#define FB_CAP 8192

typedef float vfloat4 __attribute__((ext_vector_type(4)));

static __device__ __forceinline__ float leaky(float x) { return x > 0.f ? x : NEG_SLOPE * x; }
static __device__ __forceinline__ float compf(float4 v, int i) {
    return i == 0 ? v.x : (i == 1 ? v.y : (i == 2 ? v.z : v.w));
}

// K0+HG merged: blocks [0,PT_BLOCKS) do the coarse dst-histogram; the rest compute
// Wcomb = W0 @ Wfc and bcomb = b0 @ Wfc (independent work, one launch).
__global__ void __launch_bounds__(256) k0hg(const int* __restrict__ dst, int* __restrict__ ghist,
                                            const float* __restrict__ W0, const float* __restrict__ b0,
                                            const float* __restrict__ Wfc, float* __restrict__ Wc,
                                            float* __restrict__ bc) {
    __shared__ int lh[NB];
    const int t = threadIdx.x;
    if (blockIdx.x < PT_BLOCKS) {
        for (int i = t; i < NB; i += 256) lh[i] = 0;
        __syncthreads();
        const long e0 = (long)blockIdx.x * PT_TILE;
#pragma unroll
        for (int k = 0; k < PT_TILE / 256; ++k) {
            long e = e0 + t + k * 256;
            if (e < E_EDGES) atomicAdd(&lh[dst[e] >> 7], 1);
        }
        __syncthreads();
        for (int i = t; i < NB; i += 256) {
            int v = lh[i];
            if (v) atomicAdd(&ghist[i], v);
        }
    } else {
        int tid = (int)(blockIdx.x - PT_BLOCKS) * 256 + t;
        if (tid < IN_DIM * HD) {
            int i = tid >> 7, j = tid & 127;
            float acc = 0.f;
            for (int k = 0; k < EMBED; ++k) acc += W0[i * EMBED + k] * Wfc[k * HD + j];
            Wc[tid] = acc;
        } else if (tid < IN_DIM * HD + HD) {
            int j = tid - IN_DIM * HD;
            float acc = 0.f;
            for (int k = 0; k < EMBED; ++k) acc += b0[k] * Wfc[k * HD + j];
            bc[j] = acc;
        }
    }
}

// K1 (fused with el/er): feat = fp16(feature @ Wc + bc); el/er from the fp32 accumulators.
__global__ void __launch_bounds__(256) k1_gemm(const float* __restrict__ A,
                                               const float* __restrict__ W,
                                               const float* __restrict__ b,
                                               const float* __restrict__ attn_l,
                                               const float* __restrict__ attn_r,
                                               __half* __restrict__ out,
                                               float* __restrict__ el,
                                               float* __restrict__ er) {
    __shared__ float Ws[IN_DIM * HD];   // 32 KB
    __shared__ float As[32][65];        // 8.3 KB
    __shared__ float fs[32][132];       // 16.9 KB, +4-word row stagger: conflict-free column reads
    const int t = threadIdx.x;
    const int c = t & 127, rr = t >> 7;
    const int row0 = blockIdx.x * 32;
    for (int i = t; i < IN_DIM * HD; i += 256) Ws[i] = W[i];
    for (int i = t; i < 32 * IN_DIM; i += 256) {
        int r = i >> 6, k = i & 63;
        int gr = row0 + r;
        As[r][k] = (gr < N_NODES) ? A[(size_t)gr * IN_DIM + k] : 0.f;
    }
    __syncthreads();
    float acc[16];
#pragma unroll
    for (int i = 0; i < 16; ++i) acc[i] = 0.f;
    for (int k = 0; k < IN_DIM; ++k) {
        float w = Ws[k * HD + c];
#pragma unroll
        for (int i = 0; i < 16; ++i) acc[i] += As[rr * 16 + i][k] * w;
    }
    const float bb = b[c];
#pragma unroll
    for (int i = 0; i < 16; ++i) {
        int gr = row0 + rr * 16 + i;
        float fv = acc[i] + bb;
        fs[rr * 16 + i][c] = fv;
        if (gr < N_NODES) out[(size_t)gr * HD + c] = __float2half(fv);
    }
    __syncthreads();
    // el/er: 8 threads per row, 16 channels each; chunk pairs combine to one head.
    const int r = t >> 3, q = t & 7, c0 = q * 16, h = q >> 1;
    float pl = 0.f, pr = 0.f;
#pragma unroll
    for (int k = 0; k < 16; ++k) {
        float f = fs[r][c0 + k];
        pl += f * attn_l[c0 + k];
        pr += f * attn_r[c0 + k];
    }
    pl += __shfl_xor(pl, 1);
    pr += __shfl_xor(pr, 1);
    if ((t & 1) == 0) {
        int n = row0 + r;
        if (n < N_NODES) {
            el[n * 4 + h] = pl;
            er[n * 4 + h] = pr;
        }
    }
}

// SC: exclusive scan of NB coarse counts -> coarse_start + cursor (one wave)
__global__ void __launch_bounds__(64) sc_scan(const int* __restrict__ ghist,
                                              int* __restrict__ coarse_start,
                                              int* __restrict__ cursorp) {
    const int lane = threadIdx.x;
    int run = 0;
    for (int c = 0; c < (NB + 63) / 64; ++c) {
        int i = c * 64 + lane;
        int v = (i < NB) ? ghist[i] : 0;
        int incl = v;
#pragma unroll
        for (int off = 1; off < 64; off <<= 1) {
            int o = __shfl_up(incl, off, 64);
            if (lane >= off) incl += o;
        }
        if (i < NB) {
            coarse_start[i] = run + incl - v;
            cursorp[i] = run + incl - v;
        }
        run += __shfl(incl, 63, 64);
    }
    if (lane == 0) coarse_start[NB] = E_EDGES;
}

// PT: partition edges into coarse buckets with LDS reorder -> coalesced packed flush
// part record: (dst&127)<<17 | src   (src < 2^17)
__global__ void __launch_bounds__(256) pt_partition(const int* __restrict__ src,
                                                    const int* __restrict__ dst,
                                                    int* __restrict__ cursorp,
                                                    int* __restrict__ part) {
    __shared__ int hist[NB], offs[NB], lcur[NB], base_s[NB];
    __shared__ int2 stage[PT_TILE];
    const int t = threadIdx.x, lane = t & 63, wid = t >> 6;
    const long e0 = (long)blockIdx.x * PT_TILE;
    const int cnt = (int)min((long)PT_TILE, (long)E_EDGES - e0);
    for (int i = t; i < NB; i += 256) hist[i] = 0;
    __syncthreads();
    int dv[PT_TILE / 256], sv[PT_TILE / 256];
#pragma unroll
    for (int k = 0; k < PT_TILE / 256; ++k) {
        int i = t + k * 256;
        if (i < cnt) {
            dv[k] = dst[e0 + i];
            sv[k] = src[e0 + i];
            atomicAdd(&hist[dv[k] >> 7], 1);
        } else dv[k] = -1;
    }
    __syncthreads();
    if (wid == 0) {
        int run = 0;
        for (int c = 0; c < (NB + 63) / 64; ++c) {
            int i = c * 64 + lane;
            int v = (i < NB) ? hist[i] : 0;
            int incl = v;
#pragma unroll
            for (int off = 1; off < 64; off <<= 1) {
                int o = __shfl_up(incl, off, 64);
                if (lane >= off) incl += o;
            }
            if (i < NB) offs[i] = run + incl - v;
            run += __shfl(incl, 63, 64);
        }
    }
    __syncthreads();
    for (int i = t; i < NB; i += 256) {
        lcur[i] = offs[i];
        int h = hist[i];
        base_s[i] = h ? atomicAdd(&cursorp[i], h) : 0;
    }
    __syncthreads();
#pragma unroll
    for (int k = 0; k < PT_TILE / 256; ++k) {
        if (dv[k] >= 0) {
            int b = dv[k] >> 7;
            int pos = atomicAdd(&lcur[b], 1);
            stage[pos] = make_int2(dv[k], sv[k]);
        }
    }
    __syncthreads();
    for (int i = t; i < cnt; i += 256) {
        int2 p = stage[i];
        int b = p.x >> 7;
        part[base_s[b] + (i - offs[b])] = ((p.x & 127) << 17) | p.y;
    }
}

// FB: per-bucket fine fill: local deg/scan -> rowstart, LDS place -> coalesced csr_src
__global__ void __launch_bounds__(256) fb_fill(const int* __restrict__ part,
                                               const int* __restrict__ coarse_start,
                                               int* __restrict__ rowstart,
                                               int* __restrict__ csr_src) {
    const int b = blockIdx.x, t = threadIdx.x, lane = t & 63, wid = t >> 6;
    const int s0 = coarse_start[b], s1 = coarse_start[b + 1];
    const int cnt = s1 - s0;
    __shared__ int degl[128], offl[128], curl[128];
    __shared__ int lsrc[FB_CAP];
    if (t < 128) degl[t] = 0;
    __syncthreads();
    for (int i = t; i < cnt; i += 256) {
        int p = part[s0 + i];
        atomicAdd(&degl[p >> 17], 1);
    }
    __syncthreads();
    if (wid == 0) {
        int run = 0;
        for (int c = 0; c < 2; ++c) {
            int i = c * 64 + lane;
            int v = degl[i];
            int incl = v;
#pragma unroll
            for (int off = 1; off < 64; off <<= 1) {
                int o = __shfl_up(incl, off, 64);
                if (lane >= off) incl += o;
            }
            offl[i] = run + incl - v;
            run += __shfl(incl, 63, 64);
        }
    }
    __syncthreads();
    if (t < 128) {
        curl[t] = offl[t];
        int node = b * 128 + t;
        if (node < N_NODES) rowstart[node] = s0 + offl[t];
    }
    if (b == 0 && t == 0) rowstart[N_NODES] = E_EDGES;
    __syncthreads();
    if (cnt <= FB_CAP) {
        for (int i = t; i < cnt; i += 256) {
            int p = part[s0 + i];
            int pos = atomicAdd(&curl[p >> 17], 1);
            lsrc[pos] = p & 0x1FFFF;
        }
        __syncthreads();
        for (int i = t; i < cnt; i += 256) csr_src[s0 + i] = lsrc[i];
    } else {
        for (int i = t; i < cnt; i += 256) {
            int p = part[s0 + i];
            int pos = atomicAdd(&curl[p >> 17], 1);
            csr_src[s0 + pos] = p & 0x1FFFF;
        }
    }
}

// K6: per-dst softmax stats + message aggregation. One wave per dst.
// Pass 1 stashes per-edge av[4]/src in LDS; pass 2 is pure ds_read + gather + fma.
__global__ void __launch_bounds__(256) k6_aggregate(
    const int* __restrict__ csr_src, const int* __restrict__ rowstart,
    const float* __restrict__ el, const float* __restrict__ er,
    const __half* __restrict__ feat, const float* __restrict__ gat_bias,
    float* __restrict__ mrd, float* __restrict__ hn) {
    __shared__ float s_av[4][64][4];  // [wave][edge][head], 4 KB
    __shared__ int s_src[4][64];      // 1 KB
    const int wid = threadIdx.x >> 6;
    const int lane = threadIdx.x & 63;
    const int n = blockIdx.x * 4 + wid;
    if (n >= N_NODES) return;
    const int start = rowstart[n];
    const int end = rowstart[n + 1];
    const int deg = end - start;
    const float4 er4 = *(const float4*)(er + n * 4);

    // ---- pass 1: per-head max + exp-sum; lane l owns edge start+l (deg<=64 case) ----
    int esrc = 0;
    float4 eh0 = make_float4(0.f, 0.f, 0.f, 0.f);
    const bool valid = lane < deg;
    float4 mx = make_float4(-INFINITY, -INFINITY, -INFINITY, -INFINITY);
    if (valid) {
        esrc = csr_src[start + lane];
        const float4 elv = *(const float4*)(el + esrc * 4);
        eh0.x = leaky(elv.x + er4.x);
        eh0.y = leaky(elv.y + er4.y);
        eh0.z = leaky(elv.z + er4.z);
        eh0.w = leaky(elv.w + er4.w);
        mx = eh0;
    }
    for (int e = start + lane + 64; e < end; e += 64) {  // deg>64: essentially never
        int s = csr_src[e];
        const float4 elv = *(const float4*)(el + s * 4);
        mx.x = fmaxf(mx.x, leaky(elv.x + er4.x));
        mx.y = fmaxf(mx.y, leaky(elv.y + er4.y));
        mx.z = fmaxf(mx.z, leaky(elv.z + er4.z));
        mx.w = fmaxf(mx.w, leaky(elv.w + er4.w));
    }
#pragma unroll
    for (int off = 32; off; off >>= 1) {
        mx.x = fmaxf(mx.x, __shfl_xor(mx.x, off));
        mx.y = fmaxf(mx.y, __shfl_xor(mx.y, off));
        mx.z = fmaxf(mx.z, __shfl_xor(mx.z, off));
        mx.w = fmaxf(mx.w, __shfl_xor(mx.w, off));
    }
    float4 sm = make_float4(0.f, 0.f, 0.f, 0.f);
    if (valid) {
        sm.x = __expf(eh0.x - mx.x);
        sm.y = __expf(eh0.y - mx.y);
        sm.z = __expf(eh0.z - mx.z);
        sm.w = __expf(eh0.w - mx.w);
    }
    const float4 ex = sm;  // this lane's own-edge exp, before any accumulation
    for (int e = start + lane + 64; e < end; e += 64) {
        int s = csr_src[e];
        const float4 elv = *(const float4*)(el + s * 4);
        sm.x += __expf(leaky(elv.x + er4.x) - mx.x);
        sm.y += __expf(leaky(elv.y + er4.y) - mx.y);
        sm.z += __expf(leaky(elv.z + er4.z) - mx.z);
        sm.w += __expf(leaky(elv.w + er4.w) - mx.w);
    }
#pragma unroll
    for (int off = 32; off; off >>= 1) {
        sm.x += __shfl_xor(sm.x, off);
        sm.y += __shfl_xor(sm.y, off);
        sm.z += __shfl_xor(sm.z, off);
        sm.w += __shfl_xor(sm.w, off);
    }
    float4 rd;
    rd.x = sm.x > 0.f ? 1.f / sm.x : 0.f;
    rd.y = sm.y > 0.f ? 1.f / sm.y : 0.f;
    rd.z = sm.z > 0.f ? 1.f / sm.z : 0.f;
    rd.w = sm.w > 0.f ? 1.f / sm.w : 0.f;
    if (lane == 0) {
        ((float4*)mrd)[(size_t)n * 2] = mx;
        ((float4*)mrd)[(size_t)n * 2 + 1] = rd;
    }
    // stash per-edge attention + src (zeros for invalid lanes -> pass 2 needs no predication)
    vfloat4 av4;
    av4.x = ex.x * rd.x;
    av4.y = ex.y * rd.y;
    av4.z = ex.z * rd.z;
    av4.w = ex.w * rd.w;
    s_src[wid][lane] = valid ? esrc : 0;
    *(vfloat4*)(&s_av[wid][lane][0]) = av4;

    // ---- pass 2: 16 lanes per edge (16B fp16 each = 8 channels, one head per lane) ----
    const int g4 = lane >> 4, gl = lane & 15;
    const int h = gl >> 2;
    float4 a0 = make_float4(0.f, 0.f, 0.f, 0.f);
    float4 a1 = make_float4(0.f, 0.f, 0.f, 0.f);

    if (deg <= 64) {
        const int iters = (deg + 3) >> 2;
        int idx = g4;
        for (int it = 0; it < iters; ++it, idx += 4) {
            const float av = s_av[wid][idx][h];
            const int cs = s_src[wid][idx];
            const float4 raw = ((const float4*)(feat + (size_t)cs * HD))[gl];
            const __half2* hp2 = (const __half2*)&raw;
            const float2 p0 = __half22float2(hp2[0]);
            const float2 p1 = __half22float2(hp2[1]);
            const float2 p2 = __half22float2(hp2[2]);
            const float2 p3 = __half22float2(hp2[3]);
            a0.x += av * p0.x; a0.y += av * p0.y;
            a0.z += av * p1.x; a0.w += av * p1.y;
            a1.x += av * p2.x; a1.y += av * p2.y;
            a1.z += av * p3.x; a1.w += av * p3.y;
        }
    } else {
        const float mh = compf(mx, h), rh = compf(rd, h);
        const float erh = compf(er4, h);
        for (int e = start + g4; e < end; e += 4) {
            const int s = csr_src[e];
            const float eh = leaky(el[s * 4 + h] + erh);
            const float av = __expf(eh - mh) * rh;
            const float4 raw = ((const float4*)(feat + (size_t)s * HD))[gl];
            const __half2* hp2 = (const __half2*)&raw;
            const float2 p0 = __half22float2(hp2[0]);
            const float2 p1 = __half22float2(hp2[1]);
            const float2 p2 = __half22float2(hp2[2]);
            const float2 p3 = __half22float2(hp2[3]);
            a0.x += av * p0.x; a0.y += av * p0.y;
            a0.z += av * p1.x; a0.w += av * p1.y;
            a1.x += av * p2.x; a1.y += av * p2.y;
            a1.z += av * p3.x; a1.w += av * p3.y;
        }
    }
#pragma unroll
    for (int off = 16; off <= 32; off <<= 1) {
        a0.x += __shfl_xor(a0.x, off);
        a0.y += __shfl_xor(a0.y, off);
        a0.z += __shfl_xor(a0.z, off);
        a0.w += __shfl_xor(a0.w, off);
        a1.x += __shfl_xor(a1.x, off);
        a1.y += __shfl_xor(a1.y, off);
        a1.z += __shfl_xor(a1.z, off);
        a1.w += __shfl_xor(a1.w, off);
    }
    if (lane < 16) {
        const float4 b0 = ((const float4*)gat_bias)[gl * 2];
        const float4 b1 = ((const float4*)gat_bias)[gl * 2 + 1];
        float4* hp = (float4*)(hn + (size_t)n * HD + gl * 8);
        hp[0] = make_float4(a0.x + b0.x, a0.y + b0.y, a0.z + b0.z, a0.w + b0.w);
        hp[1] = make_float4(a1.x + b1.x, a1.y + b1.y, a1.z + b1.z, a1.w + b1.w);
    }
}

// K6b: attention coefficients in edge order (coalesced nontemporal writes)
__global__ void __launch_bounds__(256) k6b_attn(
    const int* __restrict__ src, const int* __restrict__ dst,
    const float* __restrict__ el, const float* __restrict__ er,
    const float* __restrict__ mrd, float* __restrict__ a_out) {
    int e = blockIdx.x * 256 + threadIdx.x;
    if (e >= E_EDGES) return;
    const int s = src[e], d = dst[e];
    const float4 el4 = *(const float4*)(el + s * 4);
    const float4 er4 = *(const float4*)(er + d * 4);
    const float4 m4 = ((const float4*)mrd)[(size_t)d * 2];
    const float4 r4 = ((const float4*)mrd)[(size_t)d * 2 + 1];
    vfloat4 a;
    a.x = __expf(leaky(el4.x + er4.x) - m4.x) * r4.x;
    a.y = __expf(leaky(el4.y + er4.y) - m4.y) * r4.y;
    a.z = __expf(leaky(el4.z + er4.z) - m4.z) * r4.z;
    a.w = __expf(leaky(el4.w + er4.w) - m4.w) * r4.w;
    __builtin_nontemporal_store(a, (vfloat4*)a_out + e);
}

// K7: deterministic f64 mean-pool (graph_ids sorted -> contiguous ranges) + f64 MLP.
__global__ void __launch_bounds__(512) k7_pool_mlp(
    const float* __restrict__ hn, const int* __restrict__ graph_ids,
    const float* __restrict__ W1, const float* __restrict__ b1,
    const float* __restrict__ W2, const float* __restrict__ b2,
    const float* __restrict__ W3, const float* __restrict__ b3,
    float* __restrict__ out) {
    const int g = blockIdx.x, t = threadIdx.x;
    const int tt = t & 127, part = t >> 7;
    __shared__ int bounds[2];
    __shared__ double pool[4][128];
    __shared__ double x[128], y[128];
    if (t < 2) {
        const int target = g + t;
        int lo = 0, hi = N_NODES;
        while (lo < hi) {
            int mid = (lo + hi) >> 1;
            if (graph_ids[mid] < target) lo = mid + 1; else hi = mid;
        }
        bounds[t] = lo;
    }
    __syncthreads();
    const int lo = bounds[0], hi = bounds[1];
    double s = 0.0;
    for (int n = lo + part; n < hi; n += 4) s += (double)hn[(size_t)n * HD + tt];
    pool[part][tt] = s;
    __syncthreads();
    if (t < 128) {
        const double cnt = (double)(hi - lo);
        const double sum = pool[0][t] + pool[1][t] + pool[2][t] + pool[3][t];
        const double v = sum / fmax(cnt, 1.0);
        x[t] = v > 0.0 ? v : expm1(v);
    }
    __syncthreads();
    if (t < 128) {
        double acc = (double)b1[t];
        for (int k = 0; k < HD; ++k) acc += x[k] * (double)W1[k * D1 + t];
        y[t] = acc > 0.0 ? acc : expm1(acc);
    }
    __syncthreads();
    if (t < D2) {
        double a2 = (double)b2[t];
        for (int k = 0; k < D1; ++k) a2 += y[k] * (double)W2[k * D2 + t];
        x[t] = a2 > 0.0 ? a2 : expm1(a2);
    }
    __syncthreads();
    if (t < D3) {
        double a3 = (double)b3[t];
        for (int k = 0; k < D2; ++k) a3 += x[k] * (double)W3[k * D3 + t];
        out[g * D3 + t] = (float)a3;
    }
}

extern "C" void kernel_launch(void* const* d_in, const int* in_sizes, int n_in,
                              void* d_out, int out_size, void* d_ws, size_t ws_size,
                              hipStream_t stream) {
    const float* feature = (const float*)d_in[0];
    const int* src = (const int*)d_in[1];
    const int* dst = (const int*)d_in[2];
    const int* graph_ids = (const int*)d_in[3];
    const float* W0 = (const float*)d_in[4];
    const float* b0 = (const float*)d_in[5];
    const float* Wfc = (const float*)d_in[6];
    const float* attn_l = (const float*)d_in[7];
    const float* attn_r = (const float*)d_in[8];
    const float* gat_bias = (const float*)d_in[9];
    const float* W1 = (const float*)d_in[10];
    const float* b1 = (const float*)d_in[11];
    const float* W2 = (const float*)d_in[12];
    const float* b2 = (const float*)d_in[13];
    const float* W3 = (const float*)d_in[14];
    const float* b3 = (const float*)d_in[15];

    char* ws = (char*)d_ws;
    size_t off = 0;
    auto carve = [&](size_t bytes) -> void* {
        void* p = ws + off;
        off += (bytes + 255) & ~(size_t)255;
        return p;
    };
    // zero-initialized region first (single small memset)
    int* ghist = (int*)carve((size_t)NB * 4);
    const size_t zero_span = off;
    int* coarse_start = (int*)carve((size_t)(NB + 1) * 4);
    int* cursorp = (int*)carve((size_t)NB * 4);
    float* Wc = (float*)carve((size_t)IN_DIM * HD * 4);
    float* bc = (float*)carve((size_t)HD * 4);
    __half* feat = (__half*)carve((size_t)N_NODES * HD * 2);
    float* el = (float*)carve((size_t)N_NODES * 4 * 4);
    float* er = (float*)carve((size_t)N_NODES * 4 * 4);
    int* rowstart = (int*)carve((size_t)(N_NODES + 1) * 4);
    int* part = (int*)carve((size_t)E_EDGES * 4);
    int* csr_src = (int*)carve((size_t)E_EDGES * 4);
    float* mrd = (float*)carve((size_t)N_NODES * 8 * 4);

    float* out = (float*)d_out;
    // atten region of d_out doubles as hn scratch: K6 writes hn, K7 reads it,
    // THEN K6b overwrites the region with the final attention output.
    // (N*HD == E*NHEAD == 6.4M floats exactly.)
    float* hn = out + G_GRAPHS * D3;
    float* a_out = hn;

    (void)hipMemsetAsync(d_ws, 0, zero_span, stream);
    k0hg<<<PT_BLOCKS + 33, 256, 0, stream>>>(dst, ghist, W0, b0, Wfc, Wc, bc);
    k1_gemm<<<(N_NODES + 31) / 32, 256, 0, stream>>>(feature, Wc, bc, attn_l, attn_r,
                                                     feat, el, er);
    sc_scan<<<1, 64, 0, stream>>>(ghist, coarse_start, cursorp);
    pt_partition<<<PT_BLOCKS, 256, 0, stream>>>(src, dst, cursorp, part);
    fb_fill<<<NB, 256, 0, stream>>>(part, coarse_start, rowstart, csr_src);
    k6_aggregate<<<(N_NODES + 3) / 4, 256, 0, stream>>>(csr_src, rowstart, el, er, feat,
                                                        gat_bias, mrd, hn);
    k7_pool_mlp<<<G_GRAPHS, 512, 0, stream>>>(hn, graph_ids, W1, b1, W2, b2, W3, b3, out);
    k6b_attn<<<(E_EDGES + 255) / 256, 256, 0, stream>>>(src, dst, el, er, mrd, a_out);
}